// Round 11
// baseline (424.973 us; speedup 1.0000x reference)
//
#include <hip/hip_runtime.h>

#define D 128
#define EDIM 64
#define NODE_F 32
#define EDGE_F 16
#define B_PAIRS 256
#define MAXN 64
#define PROP_STEPS 3

typedef __attribute__((ext_vector_type(4))) short short4v;
typedef __attribute__((ext_vector_type(8))) short short8;
typedef __attribute__((ext_vector_type(16))) float floatx16;

__device__ __forceinline__ short f2bf(float x) {
  unsigned u = __float_as_uint(x);
  u = (u + 0x7fff + ((u >> 16) & 1)) >> 16;   // RNE
  return (short)u;
}

__device__ __forceinline__ float bf2f(short s) {
  return __uint_as_float(((unsigned)(unsigned short)s) << 16);
}

// ---------------- fused weight prep + histogram + inv init (block-range) ----------------
__global__ __launch_bounds__(256) void init_kernel(
    const float* __restrict__ W_node, const float* __restrict__ W_edge,
    const float* __restrict__ W1, const float* __restrict__ W2,
    const float* __restrict__ Wu,
    const float* __restrict__ Wa1, const float* __restrict__ Wa2,
    short* __restrict__ Wfn, short* __restrict__ Wfe,
    short* __restrict__ Wf1a, short* __restrict__ Wf1b, short* __restrict__ Wf1e,
    short* __restrict__ Wf2, short* __restrict__ Wfu,
    short* __restrict__ Wfa1, short* __restrict__ Wfa2,
    const int* __restrict__ to_idx, int* __restrict__ deg,
    int* __restrict__ inv, int E)
{
  int bid = blockIdx.x;
  int t = threadIdx.x;
  if (bid >= 916) {
    int b2 = bid - 916;
    for (int e = b2 * 256 + t; e < E; e += 256 * 256)
      atomicAdd(&deg[to_idx[e]], 1);
    for (int i = b2 * 256 + t; i < 2 * B_PAIRS * MAXN; i += 256 * 256)
      inv[i] = -1;
    return;
  }
  int idx = bid * 256 + t;
  if (idx < 4096) {
    int step = idx >> 11, hi = (idx >> 10) & 1;
    int n = (idx >> 3) & 127, j = idx & 7;
    int k = step * 16 + hi * 8 + j;
    Wfn[idx] = f2bf(W_node[(size_t)k * 128 + n]);
  } else if (idx < 5120) {
    int i = idx - 4096;
    int hi = (i >> 9) & 1, n = (i >> 3) & 63, j = i & 7;
    int k = hi * 8 + j;
    Wfe[i] = f2bf(W_edge[(size_t)k * 64 + n]);
  } else if (idx < 37888) {
    int i = idx - 5120;
    int step = i >> 12, hi = (i >> 11) & 1;
    int n = (i >> 3) & 255, j = i & 7;
    int k = step * 16 + hi * 8 + j;
    Wf1a[i] = f2bf(W1[(size_t)k * 256 + n]);
  } else if (idx < 70656) {
    int i = idx - 37888;
    int step = i >> 12, hi = (i >> 11) & 1;
    int n = (i >> 3) & 255, j = i & 7;
    int k = step * 16 + hi * 8 + j;
    Wf1b[i] = f2bf(W1[(size_t)(128 + k) * 256 + n]);
  } else if (idx < 87040) {
    int i = idx - 70656;
    int step = i >> 12, hi = (i >> 11) & 1;
    int n = (i >> 3) & 255, j = i & 7;
    int k = step * 16 + hi * 8 + j;
    Wf1e[i] = f2bf(W1[(size_t)(256 + k) * 256 + n]);
  } else if (idx < 152576) {
    int i = idx - 87040;
    int step = i >> 12, hi = (i >> 11) & 1;
    int n = (i >> 3) & 255, j = i & 7;
    int k = step * 16 + hi * 8 + j;
    Wf2[i] = f2bf(W2[(size_t)k * 256 + n]);
  } else if (idx < 201728) {
    int i = idx - 152576;
    int step = i >> 11, hi = (i >> 10) & 1;
    int n = (i >> 3) & 127, j = i & 7;
    int k = step * 16 + hi * 8 + j;
    Wfu[i] = f2bf(Wu[(size_t)k * 128 + n]);
  } else if (idx < 218112) {
    int i = idx - 201728;
    int step = i >> 11, hi = (i >> 10) & 1;
    int n = (i >> 3) & 127, j = i & 7;
    int k = step * 16 + hi * 8 + j;
    Wfa1[i] = f2bf(Wa1[(size_t)k * 128 + n]);
  } else if (idx < 234496) {
    int i = idx - 218112;
    int step = i >> 11, hi = (i >> 10) & 1;
    int n = (i >> 3) & 127, j = i & 7;
    int k = step * 16 + hi * 8 + j;
    Wfa2[i] = f2bf(Wa2[(size_t)k * 128 + n]);
  }
}

// ---------------- parallel 3-phase CSR scan ----------------
__global__ __launch_bounds__(1024) void scan1(const int* __restrict__ deg,
                                              int* __restrict__ partials, int N)
{
  __shared__ int red[16];
  int t = threadIdx.x;
  int n = blockIdx.x * 1024 + t;
  int v = (n < N) ? deg[n] : 0;
  for (int off = 32; off > 0; off >>= 1) v += __shfl_down(v, off);
  if ((t & 63) == 0) red[t >> 6] = v;
  __syncthreads();
  if (t == 0) {
    int s = 0;
    #pragma unroll
    for (int i = 0; i < 16; i++) s += red[i];
    partials[blockIdx.x] = s;
  }
}

__global__ __launch_bounds__(64) void scan2(int* __restrict__ partials,
                                            int* __restrict__ offsets, int B, int N)
{
  __shared__ int sp[64];
  int t = threadIdx.x;
  sp[t] = (t < B) ? partials[t] : 0;
  __syncthreads();
  if (t == 0) {
    int run = 0;
    for (int i = 0; i < B; i++) { int v = sp[i]; sp[i] = run; run += v; }
    offsets[N] = run;
  }
  __syncthreads();
  if (t < B) partials[t] = sp[t];
}

// zflag granularity = 32 (msg tile is 32 edges)
__global__ __launch_bounds__(1024) void scan3(const int* __restrict__ deg,
                                              const int* __restrict__ partials,
                                              int* __restrict__ offsets,
                                              int* __restrict__ cursor,
                                              int* __restrict__ zflag,
                                              const int* __restrict__ pos,
                                              int* __restrict__ inv, int N)
{
  __shared__ int s[1024];
  int t = threadIdx.x;
  int n = blockIdx.x * 1024 + t;
  int d = (n < N) ? deg[n] : 0;
  s[t] = d;
  __syncthreads();
  for (int off = 1; off < 1024; off <<= 1) {
    int v = 0;
    if (t >= off) v = s[t - off];
    __syncthreads();
    if (t >= off) s[t] += v;
    __syncthreads();
  }
  if (n < N) {
    int off = partials[blockIdx.x] + s[t] - d;   // exclusive prefix
    offsets[n] = off; cursor[n] = off;
    zflag[n] = (d == 0) || ((off >> 5) != ((off + d - 1) >> 5)) ? 1 : 0;
    inv[pos[n]] = n;
  }
}

__global__ __launch_bounds__(256) void scatter_csr(const int* __restrict__ to_idx,
                                                   int* __restrict__ cursor,
                                                   int* __restrict__ elist, int E)
{
  for (int e = blockIdx.x * 256 + threadIdx.x; e < E; e += gridDim.x * 256) {
    int pos = atomicAdd(&cursor[to_idx[e]], 1);
    elist[pos] = e;
  }
}

// ---------------- node encoder (P1/P2 no longer materialized) ----------------
__global__ __launch_bounds__(256, 4) void enc_nodes(
    const float* __restrict__ nf, const short* __restrict__ Wfn,
    const float* __restrict__ b_node, float* __restrict__ h,
    short* __restrict__ hb, int N)
{
  __shared__ short sN[32 * 40];
  int t = threadIdx.x;
  int ln = t & 63, w = t >> 6;
  int l31 = ln & 31, hi = ln >> 5;
  int n0 = blockIdx.x * 32;

  {
    int r = t >> 3, q = t & 7;
    float4 v = {0.f, 0.f, 0.f, 0.f};
    if (n0 + r < N) v = *(const float4*)(nf + (size_t)(n0 + r) * 32 + q * 4);
    short4v s;
    s[0] = f2bf(v.x); s[1] = f2bf(v.y); s[2] = f2bf(v.z); s[3] = f2bf(v.w);
    *(short4v*)(sN + r * 40 + q * 4) = s;
  }
  __syncthreads();

  int col = w * 32 + l31;
  floatx16 acc;
  #pragma unroll
  for (int i = 0; i < 16; i++) acc[i] = 0.f;
  #pragma unroll
  for (int step = 0; step < 2; step++) {
    short8 a = *(const short8*)(sN + l31 * 40 + step * 16 + hi * 8);
    short8 b = *(const short8*)(Wfn + (size_t)(step * 2 + hi) * 1024 + col * 8);
    acc = __builtin_amdgcn_mfma_f32_32x32x16_bf16(a, b, acc, 0, 0, 0);
  }
  float bv = b_node[col];
  #pragma unroll
  for (int reg = 0; reg < 16; reg++) {
    int row = (reg & 3) + 8 * (reg >> 2) + 4 * hi;
    int n = n0 + row;
    if (n < N) {
      float v = acc[reg] + bv;
      h[(size_t)n * 128 + col] = v;
      hb[(size_t)n * 128 + col] = f2bf(v);
    }
  }
}

// ---------------- fused message step (32-edge tile): chained-MFMA accumulation ----------------
// acc = (edge-enc)@W1e + h[from]@W1a + h[to]@W1b  -- the three-term add lives in the MFMA
// C-accumulator (no per-element VALU adds, no P1/P2 buffers). relu+bias -> one f2bf each ->
// LDS walk buffer (aliases the h staging region) -> CSR segment-sum (unchanged).
__global__ __launch_bounds__(256, 5) void msg_agg(
    const float* __restrict__ ef, const int* __restrict__ elist,
    const short* __restrict__ Wfe, const float* __restrict__ b_edge,
    const short* __restrict__ Wf1e, const float* __restrict__ b1,
    const short* __restrict__ Wf1a, const short* __restrict__ Wf1b,
    const short* __restrict__ hbf,
    const int* __restrict__ from_idx, const int* __restrict__ to_idx,
    const int* __restrict__ offsets,
    float* __restrict__ agg, int E)
{
  __shared__ short sE[32 * 24];        // 1.5 KB
  __shared__ short sF[32 * 76];        // 4.75 KB
  __shared__ short sH[2 * 32 * 136];   // 17 KB: h[from] | h[to]; aliased as sA[32*264] later
  __shared__ int eid_s[32];
  __shared__ int from_s[32], to_s[32];
  __shared__ int rend_s[32], inter_s[32];

  short* sA = sH;   // 32*264 = 8448 shorts <= 8704 available

  int t = threadIdx.x;
  int ln = t & 63, w = t >> 6;
  int l31 = ln & 31, hi = ln >> 5;
  int e0 = blockIdx.x * 32;

  if (t < 32) {
    int idx = e0 + t;
    int eid = (idx < E) ? elist[idx] : 0;
    eid_s[t] = eid;
    from_s[t] = from_idx[eid];
    to_s[t] = (idx < E) ? to_idx[eid] : -1;
  }
  __syncthreads();

  if (t < 32) {
    int nd = to_s[t];
    bool head = (t == 0) || (nd != to_s[t - 1]);
    if (head && nd >= 0) {
      int re = t + 1;
      while (re < 32 && to_s[re] == nd) re++;
      rend_s[t] = re;
      inter_s[t] = (offsets[nd] == e0 + t) && (offsets[nd + 1] == e0 + re) ? 1 : 0;
    }
  }

  // stage ef[eid] (f32 -> bf16)
  if (t < 128) {
    int r = t >> 2, q = t & 3;
    float4 v = *(const float4*)(ef + (size_t)eid_s[r] * 16 + q * 4);
    short4v s;
    s[0] = f2bf(v.x); s[1] = f2bf(v.y); s[2] = f2bf(v.z); s[3] = f2bf(v.w);
    *(short4v*)(sE + r * 24 + q * 4) = s;
  }
  // stage h[from] and h[to] (pure bf16 copy, no conversion)
  for (int i = t; i < 1024; i += 256) {
    int which = i >> 9, r = (i >> 4) & 31, c = i & 15;
    int nd = which ? to_s[r] : from_s[r];
    if (nd < 0) nd = 0;
    short8 v = *(const short8*)(hbf + (size_t)nd * 128 + c * 8);
    *(short8*)(sH + which * 4352 + r * 136 + c * 8) = v;
  }
  __syncthreads();

  // GEMM1: sF[32x64] = sE @ Wfe + b_edge (waves 0,1)
  if (w < 2) {
    int cbq = w * 32;
    floatx16 acc1;
    #pragma unroll
    for (int i = 0; i < 16; i++) acc1[i] = 0.f;
    short8 a = *(const short8*)(sE + l31 * 24 + hi * 8);
    short8 b = *(const short8*)(Wfe + (size_t)hi * 512 + (cbq + l31) * 8);
    acc1 = __builtin_amdgcn_mfma_f32_32x32x16_bf16(a, b, acc1, 0, 0, 0);
    int col = cbq + l31;
    float bv = b_edge[col];
    #pragma unroll
    for (int reg = 0; reg < 16; reg++) {
      int row = (reg & 3) + 8 * (reg >> 2) + 4 * hi;
      sF[row * 76 + col] = f2bf(acc1[reg] + bv);
    }
  }
  __syncthreads();

  // chained accumulation: acc = sF@Wf1e ; acc += sHf@Wf1a ; acc += sHt@Wf1b
  const int cb = w * 64;
  const int bc0 = (cb + l31) * 8, bc1 = (cb + 32 + l31) * 8;
  floatx16 acc[2];
  #pragma unroll
  for (int ct = 0; ct < 2; ct++)
    #pragma unroll
    for (int i = 0; i < 16; i++) acc[ct][i] = 0.f;

  #pragma unroll
  for (int step = 0; step < 4; step++) {
    short8 a = *(const short8*)(sF + l31 * 76 + step * 16 + hi * 8);
    short8 b0 = *(const short8*)(Wf1e + (size_t)(step * 2 + hi) * 2048 + bc0);
    short8 b1v = *(const short8*)(Wf1e + (size_t)(step * 2 + hi) * 2048 + bc1);
    acc[0] = __builtin_amdgcn_mfma_f32_32x32x16_bf16(a, b0,  acc[0], 0, 0, 0);
    acc[1] = __builtin_amdgcn_mfma_f32_32x32x16_bf16(a, b1v, acc[1], 0, 0, 0);
  }
  #pragma unroll
  for (int step = 0; step < 8; step++) {
    short8 a = *(const short8*)(sH + l31 * 136 + step * 16 + hi * 8);
    short8 b0 = *(const short8*)(Wf1a + (size_t)(step * 2 + hi) * 2048 + bc0);
    short8 b1v = *(const short8*)(Wf1a + (size_t)(step * 2 + hi) * 2048 + bc1);
    acc[0] = __builtin_amdgcn_mfma_f32_32x32x16_bf16(a, b0,  acc[0], 0, 0, 0);
    acc[1] = __builtin_amdgcn_mfma_f32_32x32x16_bf16(a, b1v, acc[1], 0, 0, 0);
  }
  #pragma unroll
  for (int step = 0; step < 8; step++) {
    short8 a = *(const short8*)(sH + 4352 + l31 * 136 + step * 16 + hi * 8);
    short8 b0 = *(const short8*)(Wf1b + (size_t)(step * 2 + hi) * 2048 + bc0);
    short8 b1v = *(const short8*)(Wf1b + (size_t)(step * 2 + hi) * 2048 + bc1);
    acc[0] = __builtin_amdgcn_mfma_f32_32x32x16_bf16(a, b0,  acc[0], 0, 0, 0);
    acc[1] = __builtin_amdgcn_mfma_f32_32x32x16_bf16(a, b1v, acc[1], 0, 0, 0);
  }
  __syncthreads();   // all reads of sH done -> safe to overwrite as sA

  // bias + relu -> bf16 walk buffer
  #pragma unroll
  for (int ct = 0; ct < 2; ct++) {
    int col = cb + ct * 32 + l31;
    float bv = b1[col];
    #pragma unroll
    for (int reg = 0; reg < 16; reg++) {
      int row = (reg & 3) + 8 * (reg >> 2) + 4 * hi;
      sA[row * 264 + col] = f2bf(fmaxf(acc[ct][reg] + bv, 0.f));
    }
  }
  __syncthreads();

  // CSR segment walk -> agg
  {
    int c = t;
    for (int r = 0; r < 32; ) {
      int nd = to_s[r];
      if (nd < 0) break;
      int re = rend_s[r];
      float a = 0.f;
      for (int i = r; i < re; i++)
        a += bf2f(sA[i * 264 + c]);
      float* dst = agg + (size_t)nd * 256 + c;
      if (inter_s[r]) *dst = a;
      else unsafeAtomicAdd(dst, a);
      r = re;
    }
  }
}

// ---------------- node update: GEMM2 (S@W2 + deg*b2) + update GEMM (no P-phase) ----------------
__global__ __launch_bounds__(256, 4) void update_mfma(
    float* __restrict__ h, short* __restrict__ hbf, float* __restrict__ agg,
    const short* __restrict__ Wf2, const float* __restrict__ b2,
    const int* __restrict__ deg,
    const short* __restrict__ Wfu, const float* __restrict__ bu,
    const int* __restrict__ zflag, int N)
{
  __shared__ short sA2[32 * 136];
  __shared__ short sS[32 * 264];
  __shared__ int zf_s[32];
  __shared__ int deg_s[32];

  int t = threadIdx.x;
  int ln = t & 63, w = t >> 6;
  int l31 = ln & 31, hi = ln >> 5;
  int n0 = blockIdx.x * 32;

  if (t < 32) {
    zf_s[t] = (n0 + t < N) ? zflag[n0 + t] : 0;
    deg_s[t] = (n0 + t < N) ? deg[n0 + t] : 0;
  }

  for (int i = t; i < 512; i += 256) {
    int r = i >> 4, c = i & 15;
    short8 v = {0, 0, 0, 0, 0, 0, 0, 0};
    if (n0 + r < N) v = *(const short8*)(hbf + (size_t)(n0 + r) * 128 + c * 8);
    *(short8*)(sA2 + r * 136 + c * 8) = v;
  }
  for (int i = t; i < 2048; i += 256) {
    int r = i >> 6, c4 = i & 63;
    int2 pk = {0, 0};
    if (n0 + r < N) {
      float4 v = *(const float4*)(agg + (size_t)(n0 + r) * 256 + c4 * 4);
      pk.x = (int)(unsigned short)f2bf(v.x) | ((int)(unsigned short)f2bf(v.y) << 16);
      pk.y = (int)(unsigned short)f2bf(v.z) | ((int)(unsigned short)f2bf(v.w) << 16);
    }
    *(int2*)(sS + r * 264 + c4 * 4) = pk;
  }
  __syncthreads();

  {
    float4 z = {0.f, 0.f, 0.f, 0.f};
    for (int i = t; i < 2048; i += 256) {
      int r = i >> 6, c4 = i & 63;
      if (n0 + r < N && zf_s[r])
        *(float4*)(agg + (size_t)(n0 + r) * 256 + c4 * 4) = z;
    }
  }

  // GEMM2: M[32x256] = sS @ Wf2 (accumulate in registers)
  floatx16 macc[2];
  int cb2 = w * 64;
  {
    const int bc0 = (cb2 + l31) * 8, bc1 = (cb2 + 32 + l31) * 8;
    #pragma unroll
    for (int ct = 0; ct < 2; ct++)
      #pragma unroll
      for (int i = 0; i < 16; i++) macc[ct][i] = 0.f;

    #pragma unroll
    for (int step = 0; step < 16; step++) {
      short8 a = *(const short8*)(sS + l31 * 264 + step * 16 + hi * 8);
      short8 b0 = *(const short8*)(Wf2 + (size_t)(step * 2 + hi) * 2048 + bc0);
      short8 b1v = *(const short8*)(Wf2 + (size_t)(step * 2 + hi) * 2048 + bc1);
      macc[0] = __builtin_amdgcn_mfma_f32_32x32x16_bf16(a, b0,  macc[0], 0, 0, 0);
      macc[1] = __builtin_amdgcn_mfma_f32_32x32x16_bf16(a, b1v, macc[1], 0, 0, 0);
    }
  }
  __syncthreads();   // all waves done READING sS -> safe to overwrite

  // write M + deg*b2 (bf16) in place of sS
  {
    #pragma unroll
    for (int ct = 0; ct < 2; ct++) {
      int col = cb2 + ct * 32 + l31;
      float bv2 = b2[col];
      #pragma unroll
      for (int reg = 0; reg < 16; reg++) {
        int row = (reg & 3) + 8 * (reg >> 2) + 4 * hi;
        sS[row * 264 + col] = f2bf(macc[ct][reg] + (float)deg_s[row] * bv2);
      }
    }
  }
  __syncthreads();

  // update GEMM: A = [hbf | M] -> steps 0..7 from sA2, steps 8..23 from sS
  const int bcol = (w * 32 + l31) * 8;

  floatx16 acc;
  #pragma unroll
  for (int i = 0; i < 16; i++) acc[i] = 0.f;

  {
    auto aptr = [&](int step) -> const short* {
      int kb = step * 16 + hi * 8;
      return (step < 8) ? (sA2 + l31 * 136 + kb) : (sS + l31 * 264 + (kb - 128));
    };
    short8 bbuf[3];
    #pragma unroll
    for (int s = 0; s < 3; s++)
      bbuf[s] = *(const short8*)(Wfu + (size_t)(s * 2 + hi) * 1024 + bcol);
    short8 abuf[2];
    abuf[0] = *(const short8*)aptr(0);
    #pragma unroll
    for (int step = 0; step < 24; step++) {
      if (step + 1 < 24)
        abuf[(step + 1) & 1] = *(const short8*)aptr(step + 1);
      acc = __builtin_amdgcn_mfma_f32_32x32x16_bf16(abuf[step & 1], bbuf[step % 3], acc, 0, 0, 0);
      if (step + 3 < 24)
        bbuf[step % 3] = *(const short8*)(Wfu + (size_t)((step + 3) * 2 + hi) * 1024 + bcol);
    }
  }

  int col = w * 32 + l31;
  float bv = bu[col];
  #pragma unroll
  for (int reg = 0; reg < 16; reg++) {
    int row = (reg & 3) + 8 * (reg >> 2) + 4 * hi;
    int n = n0 + row;
    if (n < N) {
      float nv = h[(size_t)n * 128 + col] + acc[reg] + bv;
      h[(size_t)n * 128 + col] = nv;
      hbf[(size_t)n * 128 + col] = f2bf(nv);
    }
  }
}

// ---------------- fused stack + attention features ----------------
__global__ __launch_bounds__(256, 3) void stack_attfeat(
    const float* __restrict__ h, const int* __restrict__ inv,
    const short* __restrict__ Wfa1, const float* __restrict__ ba1,
    const short* __restrict__ Wfa2, const float* __restrict__ ba2,
    const int* __restrict__ qsizes, const int* __restrict__ csizes,
    float* __restrict__ flat, short* __restrict__ flatT, short* __restrict__ tfb)
{
  __shared__ short sA[64 * 136];
  __shared__ int nd_s[64];

  int t = threadIdx.x;
  int ln = t & 63, w = t >> 6;
  int l31 = ln & 31, hi = ln >> 5;
  int r0 = blockIdx.x * 64;

  if (t < 64) nd_s[t] = inv[r0 + t];
  __syncthreads();

  for (int i = t; i < 1024; i += 256) {
    int r = i >> 4, c = (i & 15) * 8;
    int nd = nd_s[r];
    float4 v0 = {0.f, 0.f, 0.f, 0.f}, v1 = {0.f, 0.f, 0.f, 0.f};
    if (nd >= 0) {
      v0 = *(const float4*)(h + (size_t)nd * 128 + c);
      v1 = *(const float4*)(h + (size_t)nd * 128 + c + 4);
    }
    *(float4*)(flat + (size_t)(r0 + r) * 128 + c) = v0;
    *(float4*)(flat + (size_t)(r0 + r) * 128 + c + 4) = v1;
    short8 s;
    s[0] = f2bf(v0.x); s[1] = f2bf(v0.y); s[2] = f2bf(v0.z); s[3] = f2bf(v0.w);
    s[4] = f2bf(v1.x); s[5] = f2bf(v1.y); s[6] = f2bf(v1.z); s[7] = f2bf(v1.w);
    *(short8*)(sA + r * 136 + c) = s;
  }
  __syncthreads();

  for (int i = t; i < 8192; i += 256) {
    int d = i >> 6, r = i & 63;
    flatT[(size_t)blockIdx.x * 8192 + d * 64 + r] = sA[r * 136 + d];
  }

  const int arow0 = l31 * 136, arow1 = (32 + l31) * 136;
  const int bcol = (w * 32 + l31) * 8;
  int col = w * 32 + l31;

  floatx16 acc[2];
  #pragma unroll
  for (int rg = 0; rg < 2; rg++)
    #pragma unroll
    for (int i = 0; i < 16; i++) acc[rg][i] = 0.f;

  #pragma unroll
  for (int step = 0; step < 8; step++) {
    short8 a0 = *(const short8*)(sA + arow0 + step * 16 + hi * 8);
    short8 a1 = *(const short8*)(sA + arow1 + step * 16 + hi * 8);
    short8 bfr = *(const short8*)(Wfa1 + (size_t)(step * 2 + hi) * 1024 + bcol);
    acc[0] = __builtin_amdgcn_mfma_f32_32x32x16_bf16(a0, bfr, acc[0], 0, 0, 0);
    acc[1] = __builtin_amdgcn_mfma_f32_32x32x16_bf16(a1, bfr, acc[1], 0, 0, 0);
  }

  __syncthreads();
  {
    float bv = ba1[col];
    #pragma unroll
    for (int rg = 0; rg < 2; rg++)
      #pragma unroll
      for (int reg = 0; reg < 16; reg++) {
        int row = rg * 32 + (reg & 3) + 8 * (reg >> 2) + 4 * hi;
        sA[row * 136 + col] = f2bf(fmaxf(acc[rg][reg] + bv, 0.f));
      }
  }
  __syncthreads();

  floatx16 acc2[2];
  #pragma unroll
  for (int rg = 0; rg < 2; rg++)
    #pragma unroll
    for (int i = 0; i < 16; i++) acc2[rg][i] = 0.f;

  #pragma unroll
  for (int step = 0; step < 8; step++) {
    short8 a0 = *(const short8*)(sA + arow0 + step * 16 + hi * 8);
    short8 a1 = *(const short8*)(sA + arow1 + step * 16 + hi * 8);
    short8 bfr = *(const short8*)(Wfa2 + (size_t)(step * 2 + hi) * 1024 + bcol);
    acc2[0] = __builtin_amdgcn_mfma_f32_32x32x16_bf16(a0, bfr, acc2[0], 0, 0, 0);
    acc2[1] = __builtin_amdgcn_mfma_f32_32x32x16_bf16(a1, bfr, acc2[1], 0, 0, 0);
  }

  {
    float bv = ba2[col];
    #pragma unroll
    for (int rg = 0; rg < 2; rg++)
      #pragma unroll
      for (int reg = 0; reg < 16; reg++) {
        int row = r0 + rg * 32 + (reg & 3) + 8 * (reg >> 2) + 4 * hi;
        int part = row >> 14, b = (row >> 6) & 255, pp = row & 63;
        int sz = part ? csizes[b] : qsizes[b];
        float m = (pp < sz) ? 1.f : 0.f;
        tfb[(size_t)row * 128 + col] = f2bf((acc2[rg][reg] + bv) * m);
      }
  }
}

// ---------------- per-pair score: MFMA logits + parallel softmax + MFMA PV ----------------
__global__ __launch_bounds__(256, 3) void score_kernel(
    const short* __restrict__ tfb, const float* __restrict__ flat,
    const short* __restrict__ flatT,
    const int* __restrict__ qsizes, const int* __restrict__ csizes,
    float* __restrict__ out)
{
  __shared__ float SL[64 * 65];
  __shared__ float SP2[64 * 65];
  __shared__ float rstat[128];   // [0..63]=rmax, [64..127]=1/rsum
  __shared__ float cstat[128];   // [0..63]=cmax, [64..127]=1/csum
  __shared__ float red[8];

  int b = blockIdx.x, t = threadIdx.x;
  int ln = t & 63, w = t >> 6;
  int l31 = ln & 31, hi = ln >> 5;
  const short* tqb = tfb + (size_t)b * 8192;
  const short* tcb = tfb + (size_t)(256 + b) * 8192;
  const float* sq = flat + (size_t)b * 8192;
  const float* sc = flat + (size_t)(256 + b) * 8192;
  const short* sqT = flatT + (size_t)b * 8192;
  const short* scT = flatT + (size_t)(256 + b) * 8192;
  int qs = qsizes[b], cs = csizes[b];

  {
    int rowb = (w & 1) * 32, cbq = (w >> 1) * 32;
    floatx16 acc;
    #pragma unroll
    for (int i = 0; i < 16; i++) acc[i] = 0.f;
    #pragma unroll
    for (int step = 0; step < 8; step++) {
      short8 a  = *(const short8*)(tqb + (size_t)(rowb + l31) * 128 + step * 16 + hi * 8);
      short8 bf = *(const short8*)(tcb + (size_t)(cbq + l31) * 128 + step * 16 + hi * 8);
      acc = __builtin_amdgcn_mfma_f32_32x32x16_bf16(a, bf, acc, 0, 0, 0);
    }
    int ccol = cbq + l31;
    #pragma unroll
    for (int reg = 0; reg < 16; reg++) {
      int qrow = rowb + (reg & 3) + 8 * (reg >> 2) + 4 * hi;
      SL[qrow * 65 + ccol] = (qrow < qs && ccol < cs) ? acc[reg] * 10.0f : -1e9f;
    }
  }
  __syncthreads();

  // ---- fully parallel softmax stats: quad-per-row and quad-per-col ----
  {
    int q = t >> 2, g = t & 3;           // 64 rows x 4 lanes
    const float* row = SL + q * 65 + g * 16;
    float m = -1e30f;
    #pragma unroll
    for (int i = 0; i < 16; i++) m = fmaxf(m, row[i]);
    m = fmaxf(m, __shfl_xor(m, 1));
    m = fmaxf(m, __shfl_xor(m, 2));
    float s = 0.f;
    #pragma unroll
    for (int i = 0; i < 16; i++) s += __expf(row[i] - m);
    s += __shfl_xor(s, 1);
    s += __shfl_xor(s, 2);
    if (g == 0) { rstat[q] = m; rstat[64 + q] = 1.0f / s; }
  }
  {
    int c = t >> 2, g = t & 3;           // 64 cols x 4 lanes
    const float* colp = SL + (g * 16) * 65 + c;
    float m = -1e30f;
    #pragma unroll
    for (int i = 0; i < 16; i++) m = fmaxf(m, colp[i * 65]);
    m = fmaxf(m, __shfl_xor(m, 1));
    m = fmaxf(m, __shfl_xor(m, 2));
    float s = 0.f;
    #pragma unroll
    for (int i = 0; i < 16; i++) s += __expf(colp[i * 65] - m);
    s += __shfl_xor(s, 1);
    s += __shfl_xor(s, 2);
    if (g == 0) { cstat[c] = m; cstat[64 + c] = 1.0f / s; }
  }
  __syncthreads();

  // ---- write pass: both normalizations in one sweep ----
  {
    int q = t >> 2, g = t & 3;
    float rm = rstat[q], ri = rstat[64 + q];
    bool qv = q < qs;
    #pragma unroll
    for (int i = 0; i < 16; i++) {
      int c = g * 16 + i;
      float v = SL[q * 65 + c];
      SL[q * 65 + c]  = qv ? __expf(v - rm) * ri : 0.f;
      SP2[q * 65 + c] = (c < cs) ? __expf(v - cstat[c]) * cstat[64 + c] : 0.f;
    }
  }
  __syncthreads();

  int dcol = w * 32 + l31;
  floatx16 accq[2], accc[2];
  #pragma unroll
  for (int rt = 0; rt < 2; rt++) {
    #pragma unroll
    for (int i = 0; i < 16; i++) { accq[rt][i] = 0.f; accc[rt][i] = 0.f; }
  }

  #pragma unroll
  for (int rt = 0; rt < 2; rt++) {
    #pragma unroll
    for (int step = 0; step < 4; step++) {
      int kb = step * 16 + hi * 8;
      int row = rt * 32 + l31;
      short8 a;
      #pragma unroll
      for (int j = 0; j < 8; j++) a[j] = f2bf(SL[row * 65 + kb + j]);
      short8 bf = *(const short8*)(scT + (size_t)dcol * 64 + kb);
      accq[rt] = __builtin_amdgcn_mfma_f32_32x32x16_bf16(a, bf, accq[rt], 0, 0, 0);
    }
  }
  #pragma unroll
  for (int rt = 0; rt < 2; rt++) {
    #pragma unroll
    for (int step = 0; step < 4; step++) {
      int kb = step * 16 + hi * 8;
      int crow = rt * 32 + l31;
      short8 a;
      #pragma unroll
      for (int j = 0; j < 8; j++) a[j] = f2bf(SP2[(kb + j) * 65 + crow]);
      short8 bf = *(const short8*)(sqT + (size_t)dcol * 64 + kb);
      accc[rt] = __builtin_amdgcn_mfma_f32_32x32x16_bf16(a, bf, accc[rt], 0, 0, 0);
    }
  }

  float qpart = 0.f, cpart = 0.f;
  #pragma unroll
  for (int rt = 0; rt < 2; rt++) {
    #pragma unroll
    for (int reg = 0; reg < 16; reg++) {
      int row = rt * 32 + (reg & 3) + 8 * (reg >> 2) + 4 * hi;
      qpart += fmaxf(sq[(size_t)row * 128 + dcol] - accq[rt][reg], 0.f);
      cpart += fmaxf(sc[(size_t)row * 128 + dcol] - accc[rt][reg], 0.f);
    }
  }

  for (int off = 32; off > 0; off >>= 1) {
    qpart += __shfl_down(qpart, off);
    cpart += __shfl_down(cpart, off);
  }
  if ((t & 63) == 0) { red[w] = qpart; red[w + 4] = cpart; }
  __syncthreads();
  if (t == 0) {
    float qsum = red[0] + red[1] + red[2] + red[3];
    float csum = red[4] + red[5] + red[6] + red[7];
    out[b] = fminf(-qsum, -csum);
  }
}

// ---------------- launch ----------------
extern "C" void kernel_launch(void* const* d_in, const int* in_sizes, int n_in,
                              void* d_out, int out_size, void* d_ws, size_t ws_size,
                              hipStream_t stream)
{
  const float* nf  = (const float*)d_in[0];
  const float* ef  = (const float*)d_in[1];
  const int* from_idx = (const int*)d_in[2];
  const int* to_idx   = (const int*)d_in[3];
  const int* pos      = (const int*)d_in[4];
  const int* qsz      = (const int*)d_in[5];
  const int* csz      = (const int*)d_in[6];
  const float* W_node = (const float*)d_in[7];
  const float* b_node = (const float*)d_in[8];
  const float* W_edge = (const float*)d_in[9];
  const float* b_edge = (const float*)d_in[10];
  const float* W1 = (const float*)d_in[11];
  const float* b1 = (const float*)d_in[12];
  const float* W2 = (const float*)d_in[13];
  const float* b2 = (const float*)d_in[14];
  const float* Wu = (const float*)d_in[15];
  const float* bu = (const float*)d_in[16];
  const float* Wa1 = (const float*)d_in[17];
  const float* ba1 = (const float*)d_in[18];
  const float* Wa2 = (const float*)d_in[19];
  const float* ba2 = (const float*)d_in[20];
  float* out = (float*)d_out;

  int N = in_sizes[0] / NODE_F;
  int E = in_sizes[1] / EDGE_F;
  int Epad32 = (E + 31) & ~31;
  int PAD = 2 * B_PAIRS * MAXN;   // 32768
  int NB = (N + 1023) / 1024;     // scan blocks (<=64 for N<=65536)

  float* h    = (float*)d_ws;                              // N*128 f32
  float* agg  = h + (size_t)N * D;                         // N*256 f32 (sum of relu)
  short* hb   = (short*)(agg + (size_t)N * 256);           // N*128 bf16
  short* P1f  = hb + (size_t)N * D;                        // N*256 bf16 (unused, layout kept)
  short* P2f  = P1f + (size_t)N * 256;                     // N*256 bf16 (unused, layout kept)
  short* Wfn  = P2f + (size_t)N * 256;                     // 4096
  short* Wfe  = Wfn + 4096;                                // 1024
  short* Wf1a = Wfe + 1024;                                // 32768
  short* Wf1b = Wf1a + 32768;                              // 32768
  short* Wf1e = Wf1b + 32768;                              // 16384
  short* Wf2  = Wf1e + 16384;                              // 65536
  short* Wfu  = Wf2 + 65536;                               // 49152
  short* Wfa1 = Wfu + 49152;                               // 16384
  short* Wfa2 = Wfa1 + 16384;                              // 16384
  int*   deg     = (int*)(Wfa2 + 16384);                   // N
  int*   offsets = deg + N;                                // N+1
  int*   cursor  = offsets + N + 1;                        // N
  int*   elist   = cursor + N;                             // E
  int*   inv     = elist + E;                              // PAD
  int*   zflag   = inv + PAD;                              // N
  int*   partials = zflag + N;                             // NB (<=64)
  uintptr_t pb = ((uintptr_t)(partials + 64) + 15) & ~(uintptr_t)15;
  float* flat  = (float*)pb;                               // PAD*128 f32
  short* flatT = (short*)(flat + (size_t)PAD * D);
  short* tfb16 = flatT + (size_t)PAD * D;

  hipMemsetAsync(deg, 0, (size_t)N * sizeof(int), stream);
  init_kernel<<<916 + 256, 256, 0, stream>>>(
      W_node, W_edge, W1, W2, Wu, Wa1, Wa2,
      Wfn, Wfe, Wf1a, Wf1b, Wf1e, Wf2, Wfu, Wfa1, Wfa2,
      to_idx, deg, inv, E);
  scan1<<<NB, 1024, 0, stream>>>(deg, partials, N);
  scan2<<<1, 64, 0, stream>>>(partials, offsets, NB, N);
  scan3<<<NB, 1024, 0, stream>>>(deg, partials, offsets, cursor, zflag, pos, inv, N);
  scatter_csr<<<256, 256, 0, stream>>>(to_idx, cursor, elist, E);

  enc_nodes<<<(N + 31) / 32, 256, 0, stream>>>(nf, Wfn, b_node, h, hb, N);

  hipMemsetAsync(agg, 0, (size_t)N * 256 * sizeof(float), stream);

  for (int s = 0; s < PROP_STEPS; s++) {
    msg_agg<<<Epad32 / 32, 256, 0, stream>>>(ef, elist, Wfe, b_edge, Wf1e, b1,
                                             Wf1a, Wf1b, hb,
                                             from_idx, to_idx, offsets, agg, E);
    update_mfma<<<(N + 31) / 32, 256, 0, stream>>>(h, hb, agg, Wf2, b2, deg,
                                                   Wfu, bu, zflag, N);
  }

  stack_attfeat<<<PAD / 64, 256, 0, stream>>>(h, inv, Wfa1, ba1, Wfa2, ba2,
                                              qsz, csz, flat, flatT, tfb16);
  score_kernel<<<B_PAIRS, 256, 0, stream>>>(tfb16, flat, flatT, qsz, csz, out);
}

// Round 12
// 383.290 us; speedup vs baseline: 1.1088x; 1.1088x over previous
//
#include <hip/hip_runtime.h>

#define D 128
#define EDIM 64
#define NODE_F 32
#define EDGE_F 16
#define B_PAIRS 256
#define MAXN 64
#define PROP_STEPS 3

typedef __attribute__((ext_vector_type(4))) short short4v;
typedef __attribute__((ext_vector_type(8))) short short8;
typedef __attribute__((ext_vector_type(16))) float floatx16;

__device__ __forceinline__ short f2bf(float x) {
  unsigned u = __float_as_uint(x);
  u = (u + 0x7fff + ((u >> 16) & 1)) >> 16;   // RNE
  return (short)u;
}

__device__ __forceinline__ float bf2f(short s) {
  return __uint_as_float(((unsigned)(unsigned short)s) << 16);
}

// HW packed f32->bf16 (RNE, bit-identical to f2bf): D[15:0]=bf16(lo), D[31:16]=bf16(hi)
__device__ __forceinline__ unsigned f2bf_pk(float lo, float hi) {
  unsigned r;
  asm("v_cvt_pk_bf16_f32 %0, %1, %2" : "=v"(r) : "v"(lo), "v"(hi));
  return r;
}

// ---------------- fused weight prep + histogram + inv init (block-range) ----------------
__global__ __launch_bounds__(256) void init_kernel(
    const float* __restrict__ W_node, const float* __restrict__ W_edge,
    const float* __restrict__ W1, const float* __restrict__ W2,
    const float* __restrict__ Wu,
    const float* __restrict__ Wa1, const float* __restrict__ Wa2,
    short* __restrict__ Wfn, short* __restrict__ Wfe,
    short* __restrict__ Wf1a, short* __restrict__ Wf1b, short* __restrict__ Wf1e,
    short* __restrict__ Wf2, short* __restrict__ Wfu,
    short* __restrict__ Wfa1, short* __restrict__ Wfa2,
    const int* __restrict__ to_idx, int* __restrict__ deg,
    int* __restrict__ inv, int E)
{
  int bid = blockIdx.x;
  int t = threadIdx.x;
  if (bid >= 916) {
    int b2 = bid - 916;
    for (int e = b2 * 256 + t; e < E; e += 256 * 256)
      atomicAdd(&deg[to_idx[e]], 1);
    for (int i = b2 * 256 + t; i < 2 * B_PAIRS * MAXN; i += 256 * 256)
      inv[i] = -1;
    return;
  }
  int idx = bid * 256 + t;
  if (idx < 4096) {
    int step = idx >> 11, hi = (idx >> 10) & 1;
    int n = (idx >> 3) & 127, j = idx & 7;
    int k = step * 16 + hi * 8 + j;
    Wfn[idx] = f2bf(W_node[(size_t)k * 128 + n]);
  } else if (idx < 5120) {
    int i = idx - 4096;
    int hi = (i >> 9) & 1, n = (i >> 3) & 63, j = i & 7;
    int k = hi * 8 + j;
    Wfe[i] = f2bf(W_edge[(size_t)k * 64 + n]);
  } else if (idx < 37888) {
    int i = idx - 5120;
    int step = i >> 12, hi = (i >> 11) & 1;
    int n = (i >> 3) & 255, j = i & 7;
    int k = step * 16 + hi * 8 + j;
    Wf1a[i] = f2bf(W1[(size_t)k * 256 + n]);
  } else if (idx < 70656) {
    int i = idx - 37888;
    int step = i >> 12, hi = (i >> 11) & 1;
    int n = (i >> 3) & 255, j = i & 7;
    int k = step * 16 + hi * 8 + j;
    Wf1b[i] = f2bf(W1[(size_t)(128 + k) * 256 + n]);
  } else if (idx < 87040) {
    int i = idx - 70656;
    int step = i >> 12, hi = (i >> 11) & 1;
    int n = (i >> 3) & 255, j = i & 7;
    int k = step * 16 + hi * 8 + j;
    Wf1e[i] = f2bf(W1[(size_t)(256 + k) * 256 + n]);
  } else if (idx < 152576) {
    int i = idx - 87040;
    int step = i >> 12, hi = (i >> 11) & 1;
    int n = (i >> 3) & 255, j = i & 7;
    int k = step * 16 + hi * 8 + j;
    Wf2[i] = f2bf(W2[(size_t)k * 256 + n]);
  } else if (idx < 201728) {
    int i = idx - 152576;
    int step = i >> 11, hi = (i >> 10) & 1;
    int n = (i >> 3) & 127, j = i & 7;
    int k = step * 16 + hi * 8 + j;
    Wfu[i] = f2bf(Wu[(size_t)k * 128 + n]);
  } else if (idx < 218112) {
    int i = idx - 201728;
    int step = i >> 11, hi = (i >> 10) & 1;
    int n = (i >> 3) & 127, j = i & 7;
    int k = step * 16 + hi * 8 + j;
    Wfa1[i] = f2bf(Wa1[(size_t)k * 128 + n]);
  } else if (idx < 234496) {
    int i = idx - 218112;
    int step = i >> 11, hi = (i >> 10) & 1;
    int n = (i >> 3) & 127, j = i & 7;
    int k = step * 16 + hi * 8 + j;
    Wfa2[i] = f2bf(Wa2[(size_t)k * 128 + n]);
  }
}

// ---------------- parallel 3-phase CSR scan ----------------
__global__ __launch_bounds__(1024) void scan1(const int* __restrict__ deg,
                                              int* __restrict__ partials, int N)
{
  __shared__ int red[16];
  int t = threadIdx.x;
  int n = blockIdx.x * 1024 + t;
  int v = (n < N) ? deg[n] : 0;
  for (int off = 32; off > 0; off >>= 1) v += __shfl_down(v, off);
  if ((t & 63) == 0) red[t >> 6] = v;
  __syncthreads();
  if (t == 0) {
    int s = 0;
    #pragma unroll
    for (int i = 0; i < 16; i++) s += red[i];
    partials[blockIdx.x] = s;
  }
}

__global__ __launch_bounds__(64) void scan2(int* __restrict__ partials,
                                            int* __restrict__ offsets, int B, int N)
{
  __shared__ int sp[64];
  int t = threadIdx.x;
  sp[t] = (t < B) ? partials[t] : 0;
  __syncthreads();
  if (t == 0) {
    int run = 0;
    for (int i = 0; i < B; i++) { int v = sp[i]; sp[i] = run; run += v; }
    offsets[N] = run;
  }
  __syncthreads();
  if (t < B) partials[t] = sp[t];
}

// zflag granularity = 32 (msg tile is 32 edges)
__global__ __launch_bounds__(1024) void scan3(const int* __restrict__ deg,
                                              const int* __restrict__ partials,
                                              int* __restrict__ offsets,
                                              int* __restrict__ cursor,
                                              int* __restrict__ zflag,
                                              const int* __restrict__ pos,
                                              int* __restrict__ inv, int N)
{
  __shared__ int s[1024];
  int t = threadIdx.x;
  int n = blockIdx.x * 1024 + t;
  int d = (n < N) ? deg[n] : 0;
  s[t] = d;
  __syncthreads();
  for (int off = 1; off < 1024; off <<= 1) {
    int v = 0;
    if (t >= off) v = s[t - off];
    __syncthreads();
    if (t >= off) s[t] += v;
    __syncthreads();
  }
  if (n < N) {
    int off = partials[blockIdx.x] + s[t] - d;   // exclusive prefix
    offsets[n] = off; cursor[n] = off;
    zflag[n] = (d == 0) || ((off >> 5) != ((off + d - 1) >> 5)) ? 1 : 0;
    inv[pos[n]] = n;
  }
}

__global__ __launch_bounds__(256) void scatter_csr(const int* __restrict__ to_idx,
                                                   int* __restrict__ cursor,
                                                   int* __restrict__ elist, int E)
{
  for (int e = blockIdx.x * 256 + threadIdx.x; e < E; e += gridDim.x * 256) {
    int pos = atomicAdd(&cursor[to_idx[e]], 1);
    elist[pos] = e;
  }
}

// ---------------- node encoder + fused P1/P2 ----------------
__global__ __launch_bounds__(256, 3) void enc_nodes_p(
    const float* __restrict__ nf, const short* __restrict__ Wfn,
    const float* __restrict__ b_node, float* __restrict__ h,
    short* __restrict__ hb,
    const short* __restrict__ Wf1a, const short* __restrict__ Wf1b,
    short* __restrict__ P1f, short* __restrict__ P2f, int N)
{
  __shared__ short sN[32 * 40];
  __shared__ short sH[32 * 136];
  int t = threadIdx.x;
  int ln = t & 63, w = t >> 6;
  int l31 = ln & 31, hi = ln >> 5;
  int n0 = blockIdx.x * 32;

  {
    int r = t >> 3, q = t & 7;
    float4 v = {0.f, 0.f, 0.f, 0.f};
    if (n0 + r < N) v = *(const float4*)(nf + (size_t)(n0 + r) * 32 + q * 4);
    int2 s;
    s.x = (int)f2bf_pk(v.x, v.y);
    s.y = (int)f2bf_pk(v.z, v.w);
    *(int2*)(sN + r * 40 + q * 4) = s;
  }
  __syncthreads();

  int col = w * 32 + l31;
  {
    floatx16 acc;
    #pragma unroll
    for (int i = 0; i < 16; i++) acc[i] = 0.f;
    #pragma unroll
    for (int step = 0; step < 2; step++) {
      short8 a = *(const short8*)(sN + l31 * 40 + step * 16 + hi * 8);
      short8 b = *(const short8*)(Wfn + (size_t)(step * 2 + hi) * 1024 + col * 8);
      acc = __builtin_amdgcn_mfma_f32_32x32x16_bf16(a, b, acc, 0, 0, 0);
    }
    float bv = b_node[col];
    #pragma unroll
    for (int reg = 0; reg < 16; reg++) {
      int row = (reg & 3) + 8 * (reg >> 2) + 4 * hi;
      int n = n0 + row;
      float v = acc[reg] + bv;
      short bf = f2bf(v);
      if (n < N) {
        h[(size_t)n * 128 + col] = v;
        hb[(size_t)n * 128 + col] = bf;
      }
      sH[row * 136 + col] = bf;
    }
  }
  __syncthreads();

  int cb = w * 64;
  const int arow = l31 * 136;
  const int bc0 = (cb + l31) * 8, bc1 = (cb + 32 + l31) * 8;
  floatx16 acc[2][2];
  #pragma unroll
  for (int o = 0; o < 2; o++)
    #pragma unroll
    for (int ct = 0; ct < 2; ct++)
      #pragma unroll
      for (int i = 0; i < 16; i++) acc[o][ct][i] = 0.f;

  #pragma unroll
  for (int step = 0; step < 8; step++) {
    short8 a = *(const short8*)(sH + arow + step * 16 + hi * 8);
    short8 ba0 = *(const short8*)(Wf1a + (size_t)(step * 2 + hi) * 2048 + bc0);
    short8 ba1 = *(const short8*)(Wf1a + (size_t)(step * 2 + hi) * 2048 + bc1);
    short8 bb0 = *(const short8*)(Wf1b + (size_t)(step * 2 + hi) * 2048 + bc0);
    short8 bb1 = *(const short8*)(Wf1b + (size_t)(step * 2 + hi) * 2048 + bc1);
    acc[0][0] = __builtin_amdgcn_mfma_f32_32x32x16_bf16(a, ba0, acc[0][0], 0, 0, 0);
    acc[0][1] = __builtin_amdgcn_mfma_f32_32x32x16_bf16(a, ba1, acc[0][1], 0, 0, 0);
    acc[1][0] = __builtin_amdgcn_mfma_f32_32x32x16_bf16(a, bb0, acc[1][0], 0, 0, 0);
    acc[1][1] = __builtin_amdgcn_mfma_f32_32x32x16_bf16(a, bb1, acc[1][1], 0, 0, 0);
  }

  #pragma unroll
  for (int ct = 0; ct < 2; ct++) {
    int pcol = cb + ct * 32 + l31;
    #pragma unroll
    for (int reg = 0; reg < 16; reg++) {
      int row = (reg & 3) + 8 * (reg >> 2) + 4 * hi;
      int n = n0 + row;
      if (n < N) {
        P1f[(size_t)n * 256 + pcol] = f2bf(acc[0][ct][reg]);
        P2f[(size_t)n * 256 + pcol] = f2bf(acc[1][ct][reg]);
      }
    }
  }
}

// ---------------- fused message step (32-edge tile): edge-encode + relu(P1+P2+Pe) + CSR segment-sum ----------------
// r10 structure; paired f32->bf16 conversions use HW v_cvt_pk_bf16_f32 (bit-identical RNE).
__global__ __launch_bounds__(256, 6) void msg_agg(
    const float* __restrict__ ef, const int* __restrict__ elist,
    const short* __restrict__ Wfe, const float* __restrict__ b_edge,
    const short* __restrict__ Wf1e, const float* __restrict__ b1,
    const short* __restrict__ P1f, const short* __restrict__ P2f,
    const int* __restrict__ from_idx, const int* __restrict__ to_idx,
    const int* __restrict__ offsets,
    float* __restrict__ agg, int E)
{
  __shared__ short sE[32 * 24];
  __shared__ short sF[32 * 76];
  __shared__ short sA[32 * 264];
  __shared__ int eid_s[32];
  __shared__ int from_s[32], to_s[32];
  __shared__ int rend_s[32], inter_s[32];

  int t = threadIdx.x;
  int ln = t & 63, w = t >> 6;
  int l31 = ln & 31, hi = ln >> 5;
  int e0 = blockIdx.x * 32;

  if (t < 32) {
    int idx = e0 + t;
    int eid = (idx < E) ? elist[idx] : 0;
    eid_s[t] = eid;
    from_s[t] = from_idx[eid];
    to_s[t] = (idx < E) ? to_idx[eid] : -1;
  }
  __syncthreads();

  if (t < 32) {
    int nd = to_s[t];
    bool head = (t == 0) || (nd != to_s[t - 1]);
    if (head && nd >= 0) {
      int re = t + 1;
      while (re < 32 && to_s[re] == nd) re++;
      rend_s[t] = re;
      inter_s[t] = (offsets[nd] == e0 + t) && (offsets[nd + 1] == e0 + re) ? 1 : 0;
    }
  }

  // stage ef[eid] (f32 -> bf16 via cvt_pk)
  if (t < 128) {
    int r = t >> 2, q = t & 3;
    float4 v = *(const float4*)(ef + (size_t)eid_s[r] * 16 + q * 4);
    int2 s;
    s.x = (int)f2bf_pk(v.x, v.y);
    s.y = (int)f2bf_pk(v.z, v.w);
    *(int2*)(sE + r * 24 + q * 4) = s;
  }
  __syncthreads();

  // GEMM1: sF[32x64] = sE @ Wfe + b_edge (waves 0,1)
  if (w < 2) {
    int cbq = w * 32;
    floatx16 acc;
    #pragma unroll
    for (int i = 0; i < 16; i++) acc[i] = 0.f;
    short8 a = *(const short8*)(sE + l31 * 24 + hi * 8);
    short8 b = *(const short8*)(Wfe + (size_t)hi * 512 + (cbq + l31) * 8);
    acc = __builtin_amdgcn_mfma_f32_32x32x16_bf16(a, b, acc, 0, 0, 0);
    int col = cbq + l31;
    float bv = b_edge[col];
    #pragma unroll
    for (int reg = 0; reg < 16; reg++) {
      int row = (reg & 3) + 8 * (reg >> 2) + 4 * hi;
      sF[row * 76 + col] = f2bf(acc[reg] + bv);
    }
  }
  __syncthreads();

  // GEMM2: Pe[32x256] = sF @ Wf1e + b1 -> sA (bf16); wave w owns 64-col quadrant
  {
    const int cb = w * 64;
    const int bc0 = (cb + l31) * 8, bc1 = (cb + 32 + l31) * 8;
    floatx16 acc[2];
    #pragma unroll
    for (int ct = 0; ct < 2; ct++)
      #pragma unroll
      for (int i = 0; i < 16; i++) acc[ct][i] = 0.f;

    #pragma unroll
    for (int step = 0; step < 4; step++) {
      short8 a = *(const short8*)(sF + l31 * 76 + step * 16 + hi * 8);
      short8 b0 = *(const short8*)(Wf1e + (size_t)(step * 2 + hi) * 2048 + bc0);
      short8 b1v = *(const short8*)(Wf1e + (size_t)(step * 2 + hi) * 2048 + bc1);
      acc[0] = __builtin_amdgcn_mfma_f32_32x32x16_bf16(a, b0,  acc[0], 0, 0, 0);
      acc[1] = __builtin_amdgcn_mfma_f32_32x32x16_bf16(a, b1v, acc[1], 0, 0, 0);
    }

    #pragma unroll
    for (int ct = 0; ct < 2; ct++) {
      int col = cb + ct * 32 + l31;
      float bv = b1[col];
      #pragma unroll
      for (int reg = 0; reg < 16; reg++) {
        int row = (reg & 3) + 8 * (reg >> 2) + 4 * hi;
        sA[row * 264 + col] = f2bf(acc[ct][reg] + bv);
      }
    }
  }
  __syncthreads();

  // RMW: sA = relu(P1[from] + P2[to] + sA); packed HW conversion on store
  for (int i = t; i < 1024; i += 256) {
    int r = i >> 5, c8 = (i & 31) * 8;
    int nd = to_s[r]; if (nd < 0) nd = 0;
    short8 a = *(const short8*)(P1f + (size_t)from_s[r] * 256 + c8);
    short8 b = *(const short8*)(P2f + (size_t)nd * 256 + c8);
    short8 c = *(short8*)(sA + r * 264 + c8);
    float v[8];
    #pragma unroll
    for (int j = 0; j < 8; j++)
      v[j] = fmaxf(bf2f(a[j]) + bf2f(b[j]) + bf2f(c[j]), 0.f);
    int4 pk;
    pk.x = (int)f2bf_pk(v[0], v[1]);
    pk.y = (int)f2bf_pk(v[2], v[3]);
    pk.z = (int)f2bf_pk(v[4], v[5]);
    pk.w = (int)f2bf_pk(v[6], v[7]);
    *(int4*)(sA + r * 264 + c8) = pk;
  }
  __syncthreads();

  // CSR segment walk -> agg
  {
    int c = t;
    for (int r = 0; r < 32; ) {
      int nd = to_s[r];
      if (nd < 0) break;
      int re = rend_s[r];
      float a = 0.f;
      for (int i = r; i < re; i++)
        a += bf2f(sA[i * 264 + c]);
      float* dst = agg + (size_t)nd * 256 + c;
      if (inter_s[r]) *dst = a;
      else unsafeAtomicAdd(dst, a);
      r = re;
    }
  }
}

// ---------------- node update: GEMM2 (S@W2 + deg*b2) + update GEMM + fused P1/P2 ----------------
// r10 structure: LDS diet (sA2/sS reuse, 25.3 KB) + launch_bounds(256,4) (no spill).
__global__ __launch_bounds__(256, 4) void update_mfma_p(
    float* __restrict__ h, short* __restrict__ hbf, float* __restrict__ agg,
    const short* __restrict__ Wf2, const float* __restrict__ b2,
    const int* __restrict__ deg,
    const short* __restrict__ Wfu, const float* __restrict__ bu,
    const short* __restrict__ Wf1a, const short* __restrict__ Wf1b,
    short* __restrict__ P1f, short* __restrict__ P2f,
    const int* __restrict__ zflag, int want_p, int N)
{
  __shared__ short sA2[32 * 136];
  __shared__ short sS[32 * 264];
  __shared__ int zf_s[32];
  __shared__ int deg_s[32];

  int t = threadIdx.x;
  int ln = t & 63, w = t >> 6;
  int l31 = ln & 31, hi = ln >> 5;
  int n0 = blockIdx.x * 32;

  if (t < 32) {
    zf_s[t] = (n0 + t < N) ? zflag[n0 + t] : 0;
    deg_s[t] = (n0 + t < N) ? deg[n0 + t] : 0;
  }

  for (int i = t; i < 512; i += 256) {
    int r = i >> 4, c = i & 15;
    short8 v = {0, 0, 0, 0, 0, 0, 0, 0};
    if (n0 + r < N) v = *(const short8*)(hbf + (size_t)(n0 + r) * 128 + c * 8);
    *(short8*)(sA2 + r * 136 + c * 8) = v;
  }
  for (int i = t; i < 2048; i += 256) {
    int r = i >> 6, c4 = i & 63;
    int2 pk = {0, 0};
    if (n0 + r < N) {
      float4 v = *(const float4*)(agg + (size_t)(n0 + r) * 256 + c4 * 4);
      pk.x = (int)f2bf_pk(v.x, v.y);
      pk.y = (int)f2bf_pk(v.z, v.w);
    }
    *(int2*)(sS + r * 264 + c4 * 4) = pk;
  }
  __syncthreads();

  {
    float4 z = {0.f, 0.f, 0.f, 0.f};
    for (int i = t; i < 2048; i += 256) {
      int r = i >> 6, c4 = i & 63;
      if (n0 + r < N && zf_s[r])
        *(float4*)(agg + (size_t)(n0 + r) * 256 + c4 * 4) = z;
    }
  }

  // GEMM2: M[32x256] = sS @ Wf2 (accumulate in registers)
  floatx16 macc[2];
  int cb2 = w * 64;
  {
    const int bc0 = (cb2 + l31) * 8, bc1 = (cb2 + 32 + l31) * 8;
    #pragma unroll
    for (int ct = 0; ct < 2; ct++)
      #pragma unroll
      for (int i = 0; i < 16; i++) macc[ct][i] = 0.f;

    #pragma unroll
    for (int step = 0; step < 16; step++) {
      short8 a = *(const short8*)(sS + l31 * 264 + step * 16 + hi * 8);
      short8 b0 = *(const short8*)(Wf2 + (size_t)(step * 2 + hi) * 2048 + bc0);
      short8 b1v = *(const short8*)(Wf2 + (size_t)(step * 2 + hi) * 2048 + bc1);
      macc[0] = __builtin_amdgcn_mfma_f32_32x32x16_bf16(a, b0,  macc[0], 0, 0, 0);
      macc[1] = __builtin_amdgcn_mfma_f32_32x32x16_bf16(a, b1v, macc[1], 0, 0, 0);
    }
  }
  __syncthreads();   // all waves done READING sS -> safe to overwrite

  // write M + deg*b2 (bf16) in place of sS
  {
    #pragma unroll
    for (int ct = 0; ct < 2; ct++) {
      int col = cb2 + ct * 32 + l31;
      float bv2 = b2[col];
      #pragma unroll
      for (int reg = 0; reg < 16; reg++) {
        int row = (reg & 3) + 8 * (reg >> 2) + 4 * hi;
        sS[row * 264 + col] = f2bf(macc[ct][reg] + (float)deg_s[row] * bv2);
      }
    }
  }
  __syncthreads();

  // update GEMM: A = [hbf | M] -> steps 0..7 from sA2, steps 8..23 from sS
  const int bcol = (w * 32 + l31) * 8;

  floatx16 acc;
  #pragma unroll
  for (int i = 0; i < 16; i++) acc[i] = 0.f;

  {
    auto aptr = [&](int step) -> const short* {
      int kb = step * 16 + hi * 8;
      return (step < 8) ? (sA2 + l31 * 136 + kb) : (sS + l31 * 264 + (kb - 128));
    };
    short8 bbuf[3];
    #pragma unroll
    for (int s = 0; s < 3; s++)
      bbuf[s] = *(const short8*)(Wfu + (size_t)(s * 2 + hi) * 1024 + bcol);
    short8 abuf[2];
    abuf[0] = *(const short8*)aptr(0);
    #pragma unroll
    for (int step = 0; step < 24; step++) {
      if (step + 1 < 24)
        abuf[(step + 1) & 1] = *(const short8*)aptr(step + 1);
      acc = __builtin_amdgcn_mfma_f32_32x32x16_bf16(abuf[step & 1], bbuf[step % 3], acc, 0, 0, 0);
      if (step + 3 < 24)
        bbuf[step % 3] = *(const short8*)(Wfu + (size_t)((step + 3) * 2 + hi) * 1024 + bcol);
    }
  }

  __syncthreads();

  int col = w * 32 + l31;
  float bv = bu[col];
  #pragma unroll
  for (int reg = 0; reg < 16; reg++) {
    int row = (reg & 3) + 8 * (reg >> 2) + 4 * hi;
    int n = n0 + row;
    float nv = 0.f;
    if (n < N) nv = h[(size_t)n * 128 + col] + acc[reg] + bv;
    short bf = f2bf(nv);
    if (n < N) {
      h[(size_t)n * 128 + col] = nv;
      hbf[(size_t)n * 128 + col] = bf;
    }
    sA2[row * 136 + col] = bf;
  }

  if (!want_p) return;
  __syncthreads();

  int cb = w * 64;
  const int bc0 = (cb + l31) * 8, bc1 = (cb + 32 + l31) * 8;
  const int arow = l31 * 136;
  floatx16 pacc[2][2];
  #pragma unroll
  for (int o = 0; o < 2; o++)
    #pragma unroll
    for (int ct = 0; ct < 2; ct++)
      #pragma unroll
      for (int i = 0; i < 16; i++) pacc[o][ct][i] = 0.f;

  #pragma unroll
  for (int step = 0; step < 8; step++) {
    short8 a = *(const short8*)(sA2 + arow + step * 16 + hi * 8);
    short8 ba0 = *(const short8*)(Wf1a + (size_t)(step * 2 + hi) * 2048 + bc0);
    short8 ba1 = *(const short8*)(Wf1a + (size_t)(step * 2 + hi) * 2048 + bc1);
    short8 bb0 = *(const short8*)(Wf1b + (size_t)(step * 2 + hi) * 2048 + bc0);
    short8 bb1 = *(const short8*)(Wf1b + (size_t)(step * 2 + hi) * 2048 + bc1);
    pacc[0][0] = __builtin_amdgcn_mfma_f32_32x32x16_bf16(a, ba0, pacc[0][0], 0, 0, 0);
    pacc[0][1] = __builtin_amdgcn_mfma_f32_32x32x16_bf16(a, ba1, pacc[0][1], 0, 0, 0);
    pacc[1][0] = __builtin_amdgcn_mfma_f32_32x32x16_bf16(a, bb0, pacc[1][0], 0, 0, 0);
    pacc[1][1] = __builtin_amdgcn_mfma_f32_32x32x16_bf16(a, bb1, pacc[1][1], 0, 0, 0);
  }

  #pragma unroll
  for (int ct = 0; ct < 2; ct++) {
    int pcol = cb + ct * 32 + l31;
    #pragma unroll
    for (int reg = 0; reg < 16; reg++) {
      int row = (reg & 3) + 8 * (reg >> 2) + 4 * hi;
      int n = n0 + row;
      if (n < N) {
        P1f[(size_t)n * 256 + pcol] = f2bf(pacc[0][ct][reg]);
        P2f[(size_t)n * 256 + pcol] = f2bf(pacc[1][ct][reg]);
      }
    }
  }
}

// ---------------- fused stack + attention features ----------------
__global__ __launch_bounds__(256, 3) void stack_attfeat(
    const float* __restrict__ h, const int* __restrict__ inv,
    const short* __restrict__ Wfa1, const float* __restrict__ ba1,
    const short* __restrict__ Wfa2, const float* __restrict__ ba2,
    const int* __restrict__ qsizes, const int* __restrict__ csizes,
    float* __restrict__ flat, short* __restrict__ flatT, short* __restrict__ tfb)
{
  __shared__ short sA[64 * 136];
  __shared__ int nd_s[64];

  int t = threadIdx.x;
  int ln = t & 63, w = t >> 6;
  int l31 = ln & 31, hi = ln >> 5;
  int r0 = blockIdx.x * 64;

  if (t < 64) nd_s[t] = inv[r0 + t];
  __syncthreads();

  for (int i = t; i < 1024; i += 256) {
    int r = i >> 4, c = (i & 15) * 8;
    int nd = nd_s[r];
    float4 v0 = {0.f, 0.f, 0.f, 0.f}, v1 = {0.f, 0.f, 0.f, 0.f};
    if (nd >= 0) {
      v0 = *(const float4*)(h + (size_t)nd * 128 + c);
      v1 = *(const float4*)(h + (size_t)nd * 128 + c + 4);
    }
    *(float4*)(flat + (size_t)(r0 + r) * 128 + c) = v0;
    *(float4*)(flat + (size_t)(r0 + r) * 128 + c + 4) = v1;
    int4 s;
    s.x = (int)f2bf_pk(v0.x, v0.y);
    s.y = (int)f2bf_pk(v0.z, v0.w);
    s.z = (int)f2bf_pk(v1.x, v1.y);
    s.w = (int)f2bf_pk(v1.z, v1.w);
    *(int4*)(sA + r * 136 + c) = s;
  }
  __syncthreads();

  for (int i = t; i < 8192; i += 256) {
    int d = i >> 6, r = i & 63;
    flatT[(size_t)blockIdx.x * 8192 + d * 64 + r] = sA[r * 136 + d];
  }

  const int arow0 = l31 * 136, arow1 = (32 + l31) * 136;
  const int bcol = (w * 32 + l31) * 8;
  int col = w * 32 + l31;

  floatx16 acc[2];
  #pragma unroll
  for (int rg = 0; rg < 2; rg++)
    #pragma unroll
    for (int i = 0; i < 16; i++) acc[rg][i] = 0.f;

  #pragma unroll
  for (int step = 0; step < 8; step++) {
    short8 a0 = *(const short8*)(sA + arow0 + step * 16 + hi * 8);
    short8 a1 = *(const short8*)(sA + arow1 + step * 16 + hi * 8);
    short8 bfr = *(const short8*)(Wfa1 + (size_t)(step * 2 + hi) * 1024 + bcol);
    acc[0] = __builtin_amdgcn_mfma_f32_32x32x16_bf16(a0, bfr, acc[0], 0, 0, 0);
    acc[1] = __builtin_amdgcn_mfma_f32_32x32x16_bf16(a1, bfr, acc[1], 0, 0, 0);
  }

  __syncthreads();
  {
    float bv = ba1[col];
    #pragma unroll
    for (int rg = 0; rg < 2; rg++)
      #pragma unroll
      for (int reg = 0; reg < 16; reg++) {
        int row = rg * 32 + (reg & 3) + 8 * (reg >> 2) + 4 * hi;
        sA[row * 136 + col] = f2bf(fmaxf(acc[rg][reg] + bv, 0.f));
      }
  }
  __syncthreads();

  floatx16 acc2[2];
  #pragma unroll
  for (int rg = 0; rg < 2; rg++)
    #pragma unroll
    for (int i = 0; i < 16; i++) acc2[rg][i] = 0.f;

  #pragma unroll
  for (int step = 0; step < 8; step++) {
    short8 a0 = *(const short8*)(sA + arow0 + step * 16 + hi * 8);
    short8 a1 = *(const short8*)(sA + arow1 + step * 16 + hi * 8);
    short8 bfr = *(const short8*)(Wfa2 + (size_t)(step * 2 + hi) * 1024 + bcol);
    acc2[0] = __builtin_amdgcn_mfma_f32_32x32x16_bf16(a0, bfr, acc2[0], 0, 0, 0);
    acc2[1] = __builtin_amdgcn_mfma_f32_32x32x16_bf16(a1, bfr, acc2[1], 0, 0, 0);
  }

  {
    float bv = ba2[col];
    #pragma unroll
    for (int rg = 0; rg < 2; rg++)
      #pragma unroll
      for (int reg = 0; reg < 16; reg++) {
        int row = r0 + rg * 32 + (reg & 3) + 8 * (reg >> 2) + 4 * hi;
        int part = row >> 14, b = (row >> 6) & 255, pp = row & 63;
        int sz = part ? csizes[b] : qsizes[b];
        float m = (pp < sz) ? 1.f : 0.f;
        tfb[(size_t)row * 128 + col] = f2bf((acc2[rg][reg] + bv) * m);
      }
  }
}

// ---------------- per-pair score: MFMA logits + parallel softmax + MFMA PV ----------------
__global__ __launch_bounds__(256, 3) void score_kernel(
    const short* __restrict__ tfb, const float* __restrict__ flat,
    const short* __restrict__ flatT,
    const int* __restrict__ qsizes, const int* __restrict__ csizes,
    float* __restrict__ out)
{
  __shared__ float SL[64 * 65];
  __shared__ float SP2[64 * 65];
  __shared__ float rstat[128];   // [0..63]=rmax, [64..127]=1/rsum
  __shared__ float cstat[128];   // [0..63]=cmax, [64..127]=1/csum
  __shared__ float red[8];

  int b = blockIdx.x, t = threadIdx.x;
  int ln = t & 63, w = t >> 6;
  int l31 = ln & 31, hi = ln >> 5;
  const short* tqb = tfb + (size_t)b * 8192;
  const short* tcb = tfb + (size_t)(256 + b) * 8192;
  const float* sq = flat + (size_t)b * 8192;
  const float* sc = flat + (size_t)(256 + b) * 8192;
  const short* sqT = flatT + (size_t)b * 8192;
  const short* scT = flatT + (size_t)(256 + b) * 8192;
  int qs = qsizes[b], cs = csizes[b];

  {
    int rowb = (w & 1) * 32, cbq = (w >> 1) * 32;
    floatx16 acc;
    #pragma unroll
    for (int i = 0; i < 16; i++) acc[i] = 0.f;
    #pragma unroll
    for (int step = 0; step < 8; step++) {
      short8 a  = *(const short8*)(tqb + (size_t)(rowb + l31) * 128 + step * 16 + hi * 8);
      short8 bf = *(const short8*)(tcb + (size_t)(cbq + l31) * 128 + step * 16 + hi * 8);
      acc = __builtin_amdgcn_mfma_f32_32x32x16_bf16(a, bf, acc, 0, 0, 0);
    }
    int ccol = cbq + l31;
    #pragma unroll
    for (int reg = 0; reg < 16; reg++) {
      int qrow = rowb + (reg & 3) + 8 * (reg >> 2) + 4 * hi;
      SL[qrow * 65 + ccol] = (qrow < qs && ccol < cs) ? acc[reg] * 10.0f : -1e9f;
    }
  }
  __syncthreads();

  // ---- fully parallel softmax stats: quad-per-row and quad-per-col ----
  {
    int q = t >> 2, g = t & 3;           // 64 rows x 4 lanes
    const float* row = SL + q * 65 + g * 16;
    float m = -1e30f;
    #pragma unroll
    for (int i = 0; i < 16; i++) m = fmaxf(m, row[i]);
    m = fmaxf(m, __shfl_xor(m, 1));
    m = fmaxf(m, __shfl_xor(m, 2));
    float s = 0.f;
    #pragma unroll
    for (int i = 0; i < 16; i++) s += __expf(row[i] - m);
    s += __shfl_xor(s, 1);
    s += __shfl_xor(s, 2);
    if (g == 0) { rstat[q] = m; rstat[64 + q] = 1.0f / s; }
  }
  {
    int c = t >> 2, g = t & 3;           // 64 cols x 4 lanes
    const float* colp = SL + (g * 16) * 65 + c;
    float m = -1e30f;
    #pragma unroll
    for (int i = 0; i < 16; i++) m = fmaxf(m, colp[i * 65]);
    m = fmaxf(m, __shfl_xor(m, 1));
    m = fmaxf(m, __shfl_xor(m, 2));
    float s = 0.f;
    #pragma unroll
    for (int i = 0; i < 16; i++) s += __expf(colp[i * 65] - m);
    s += __shfl_xor(s, 1);
    s += __shfl_xor(s, 2);
    if (g == 0) { cstat[c] = m; cstat[64 + c] = 1.0f / s; }
  }
  __syncthreads();

  // ---- write pass: both normalizations in one sweep ----
  {
    int q = t >> 2, g = t & 3;
    float rm = rstat[q], ri = rstat[64 + q];
    bool qv = q < qs;
    #pragma unroll
    for (int i = 0; i < 16; i++) {
      int c = g * 16 + i;
      float v = SL[q * 65 + c];
      SL[q * 65 + c]  = qv ? __expf(v - rm) * ri : 0.f;
      SP2[q * 65 + c] = (c < cs) ? __expf(v - cstat[c]) * cstat[64 + c] : 0.f;
    }
  }
  __syncthreads();

  int dcol = w * 32 + l31;
  floatx16 accq[2], accc[2];
  #pragma unroll
  for (int rt = 0; rt < 2; rt++) {
    #pragma unroll
    for (int i = 0; i < 16; i++) { accq[rt][i] = 0.f; accc[rt][i] = 0.f; }
  }

  #pragma unroll
  for (int rt = 0; rt < 2; rt++) {
    #pragma unroll
    for (int step = 0; step < 4; step++) {
      int kb = step * 16 + hi * 8;
      int row = rt * 32 + l31;
      short8 a;
      #pragma unroll
      for (int j = 0; j < 8; j++) a[j] = f2bf(SL[row * 65 + kb + j]);
      short8 bf = *(const short8*)(scT + (size_t)dcol * 64 + kb);
      accq[rt] = __builtin_amdgcn_mfma_f32_32x32x16_bf16(a, bf, accq[rt], 0, 0, 0);
    }
  }
  #pragma unroll
  for (int rt = 0; rt < 2; rt++) {
    #pragma unroll
    for (int step = 0; step < 4; step++) {
      int kb = step * 16 + hi * 8;
      int crow = rt * 32 + l31;
      short8 a;
      #pragma unroll
      for (int j = 0; j < 8; j++) a[j] = f2bf(SP2[(kb + j) * 65 + crow]);
      short8 bf = *(const short8*)(sqT + (size_t)dcol * 64 + kb);
      accc[rt] = __builtin_amdgcn_mfma_f32_32x32x16_bf16(a, bf, accc[rt], 0, 0, 0);
    }
  }

  float qpart = 0.f, cpart = 0.f;
  #pragma unroll
  for (int rt = 0; rt < 2; rt++) {
    #pragma unroll
    for (int reg = 0; reg < 16; reg++) {
      int row = rt * 32 + (reg & 3) + 8 * (reg >> 2) + 4 * hi;
      qpart += fmaxf(sq[(size_t)row * 128 + dcol] - accq[rt][reg], 0.f);
      cpart += fmaxf(sc[(size_t)row * 128 + dcol] - accc[rt][reg], 0.f);
    }
  }

  for (int off = 32; off > 0; off >>= 1) {
    qpart += __shfl_down(qpart, off);
    cpart += __shfl_down(cpart, off);
  }
  if ((t & 63) == 0) { red[w] = qpart; red[w + 4] = cpart; }
  __syncthreads();
  if (t == 0) {
    float qsum = red[0] + red[1] + red[2] + red[3];
    float csum = red[4] + red[5] + red[6] + red[7];
    out[b] = fminf(-qsum, -csum);
  }
}

// ---------------- launch ----------------
extern "C" void kernel_launch(void* const* d_in, const int* in_sizes, int n_in,
                              void* d_out, int out_size, void* d_ws, size_t ws_size,
                              hipStream_t stream)
{
  const float* nf  = (const float*)d_in[0];
  const float* ef  = (const float*)d_in[1];
  const int* from_idx = (const int*)d_in[2];
  const int* to_idx   = (const int*)d_in[3];
  const int* pos      = (const int*)d_in[4];
  const int* qsz      = (const int*)d_in[5];
  const int* csz      = (const int*)d_in[6];
  const float* W_node = (const float*)d_in[7];
  const float* b_node = (const float*)d_in[8];
  const float* W_edge = (const float*)d_in[9];
  const float* b_edge = (const float*)d_in[10];
  const float* W1 = (const float*)d_in[11];
  const float* b1 = (const float*)d_in[12];
  const float* W2 = (const float*)d_in[13];
  const float* b2 = (const float*)d_in[14];
  const float* Wu = (const float*)d_in[15];
  const float* bu = (const float*)d_in[16];
  const float* Wa1 = (const float*)d_in[17];
  const float* ba1 = (const float*)d_in[18];
  const float* Wa2 = (const float*)d_in[19];
  const float* ba2 = (const float*)d_in[20];
  float* out = (float*)d_out;

  int N = in_sizes[0] / NODE_F;
  int E = in_sizes[1] / EDGE_F;
  int Epad32 = (E + 31) & ~31;
  int PAD = 2 * B_PAIRS * MAXN;   // 32768
  int NB = (N + 1023) / 1024;     // scan blocks (<=64 for N<=65536)

  float* h    = (float*)d_ws;                              // N*128 f32
  float* agg  = h + (size_t)N * D;                         // N*256 f32 (sum of relu)
  short* hb   = (short*)(agg + (size_t)N * 256);           // N*128 bf16
  short* P1f  = hb + (size_t)N * D;                        // N*256 bf16
  short* P2f  = P1f + (size_t)N * 256;                     // N*256 bf16
  short* Wfn  = P2f + (size_t)N * 256;                     // 4096
  short* Wfe  = Wfn + 4096;                                // 1024
  short* Wf1a = Wfe + 1024;                                // 32768
  short* Wf1b = Wf1a + 32768;                              // 32768
  short* Wf1e = Wf1b + 32768;                              // 16384
  short* Wf2  = Wf1e + 16384;                              // 65536
  short* Wfu  = Wf2 + 65536;                               // 49152
  short* Wfa1 = Wfu + 49152;                               // 16384
  short* Wfa2 = Wfa1 + 16384;                              // 16384
  int*   deg     = (int*)(Wfa2 + 16384);                   // N
  int*   offsets = deg + N;                                // N+1
  int*   cursor  = offsets + N + 1;                        // N
  int*   elist   = cursor + N;                             // E
  int*   inv     = elist + E;                              // PAD
  int*   zflag   = inv + PAD;                              // N
  int*   partials = zflag + N;                             // NB (<=64)
  uintptr_t pb = ((uintptr_t)(partials + 64) + 15) & ~(uintptr_t)15;
  float* flat  = (float*)pb;                               // PAD*128 f32
  short* flatT = (short*)(flat + (size_t)PAD * D);
  short* tfb16 = flatT + (size_t)PAD * D;

  hipMemsetAsync(deg, 0, (size_t)N * sizeof(int), stream);
  init_kernel<<<916 + 256, 256, 0, stream>>>(
      W_node, W_edge, W1, W2, Wu, Wa1, Wa2,
      Wfn, Wfe, Wf1a, Wf1b, Wf1e, Wf2, Wfu, Wfa1, Wfa2,
      to_idx, deg, inv, E);
  scan1<<<NB, 1024, 0, stream>>>(deg, partials, N);
  scan2<<<1, 64, 0, stream>>>(partials, offsets, NB, N);
  scan3<<<NB, 1024, 0, stream>>>(deg, partials, offsets, cursor, zflag, pos, inv, N);
  scatter_csr<<<256, 256, 0, stream>>>(to_idx, cursor, elist, E);

  enc_nodes_p<<<(N + 31) / 32, 256, 0, stream>>>(nf, Wfn, b_node, h, hb,
                                                 Wf1a, Wf1b, P1f, P2f, N);

  hipMemsetAsync(agg, 0, (size_t)N * 256 * sizeof(float), stream);

  for (int s = 0; s < PROP_STEPS; s++) {
    msg_agg<<<Epad32 / 32, 256, 0, stream>>>(ef, elist, Wfe, b_edge, Wf1e, b1,
                                             P1f, P2f, from_idx, to_idx, offsets,
                                             agg, E);
    update_mfma_p<<<(N + 31) / 32, 256, 0, stream>>>(h, hb, agg, Wf2, b2, deg,
                                                     Wfu, bu, Wf1a, Wf1b, P1f, P2f, zflag,
                                                     (s + 1 < PROP_STEPS) ? 1 : 0, N);
  }

  stack_attfeat<<<PAD / 64, 256, 0, stream>>>(h, inv, Wfa1, ba1, Wfa2, ba2,
                                              qsz, csz, flat, flatT, tfb16);
  score_kernel<<<B_PAIRS, 256, 0, stream>>>(tfb16, flat, flatT, qsz, csz, out);
}

// Round 13
// 373.593 us; speedup vs baseline: 1.1375x; 1.0260x over previous
//
#include <hip/hip_runtime.h>

#define D 128
#define EDIM 64
#define NODE_F 32
#define EDGE_F 16
#define B_PAIRS 256
#define MAXN 64
#define PROP_STEPS 3

typedef __attribute__((ext_vector_type(4))) short short4v;
typedef __attribute__((ext_vector_type(8))) short short8;
typedef __attribute__((ext_vector_type(16))) float floatx16;

__device__ __forceinline__ short f2bf(float x) {
  unsigned u = __float_as_uint(x);
  u = (u + 0x7fff + ((u >> 16) & 1)) >> 16;   // RNE
  return (short)u;
}

__device__ __forceinline__ float bf2f(short s) {
  return __uint_as_float(((unsigned)(unsigned short)s) << 16);
}

// HW packed f32->bf16 (RNE, bit-identical to f2bf)
__device__ __forceinline__ unsigned f2bf_pk(float lo, float hi) {
  unsigned r;
  asm("v_cvt_pk_bf16_f32 %0, %1, %2" : "=v"(r) : "v"(lo), "v"(hi));
  return r;
}

// ---------------- fused weight prep + histogram + inv init (block-range) ----------------
__global__ __launch_bounds__(256) void init_kernel(
    const float* __restrict__ W_node, const float* __restrict__ W_edge,
    const float* __restrict__ W1, const float* __restrict__ W2,
    const float* __restrict__ Wu,
    const float* __restrict__ Wa1, const float* __restrict__ Wa2,
    short* __restrict__ Wfn, short* __restrict__ Wfe,
    short* __restrict__ Wf1a, short* __restrict__ Wf1b, short* __restrict__ Wf1e,
    short* __restrict__ Wf2, short* __restrict__ Wfu,
    short* __restrict__ Wfa1, short* __restrict__ Wfa2,
    const int* __restrict__ to_idx, int* __restrict__ deg,
    int* __restrict__ inv, int E)
{
  int bid = blockIdx.x;
  int t = threadIdx.x;
  if (bid >= 916) {
    int b2 = bid - 916;
    for (int e = b2 * 256 + t; e < E; e += 256 * 256)
      atomicAdd(&deg[to_idx[e]], 1);
    for (int i = b2 * 256 + t; i < 2 * B_PAIRS * MAXN; i += 256 * 256)
      inv[i] = -1;
    return;
  }
  int idx = bid * 256 + t;
  if (idx < 4096) {
    int step = idx >> 11, hi = (idx >> 10) & 1;
    int n = (idx >> 3) & 127, j = idx & 7;
    int k = step * 16 + hi * 8 + j;
    Wfn[idx] = f2bf(W_node[(size_t)k * 128 + n]);
  } else if (idx < 5120) {
    int i = idx - 4096;
    int hi = (i >> 9) & 1, n = (i >> 3) & 63, j = i & 7;
    int k = hi * 8 + j;
    Wfe[i] = f2bf(W_edge[(size_t)k * 64 + n]);
  } else if (idx < 37888) {
    int i = idx - 5120;
    int step = i >> 12, hi = (i >> 11) & 1;
    int n = (i >> 3) & 255, j = i & 7;
    int k = step * 16 + hi * 8 + j;
    Wf1a[i] = f2bf(W1[(size_t)k * 256 + n]);
  } else if (idx < 70656) {
    int i = idx - 37888;
    int step = i >> 12, hi = (i >> 11) & 1;
    int n = (i >> 3) & 255, j = i & 7;
    int k = step * 16 + hi * 8 + j;
    Wf1b[i] = f2bf(W1[(size_t)(128 + k) * 256 + n]);
  } else if (idx < 87040) {
    int i = idx - 70656;
    int step = i >> 12, hi = (i >> 11) & 1;
    int n = (i >> 3) & 255, j = i & 7;
    int k = step * 16 + hi * 8 + j;
    Wf1e[i] = f2bf(W1[(size_t)(256 + k) * 256 + n]);
  } else if (idx < 152576) {
    int i = idx - 87040;
    int step = i >> 12, hi = (i >> 11) & 1;
    int n = (i >> 3) & 255, j = i & 7;
    int k = step * 16 + hi * 8 + j;
    Wf2[i] = f2bf(W2[(size_t)k * 256 + n]);
  } else if (idx < 201728) {
    int i = idx - 152576;
    int step = i >> 11, hi = (i >> 10) & 1;
    int n = (i >> 3) & 127, j = i & 7;
    int k = step * 16 + hi * 8 + j;
    Wfu[i] = f2bf(Wu[(size_t)k * 128 + n]);
  } else if (idx < 218112) {
    int i = idx - 201728;
    int step = i >> 11, hi = (i >> 10) & 1;
    int n = (i >> 3) & 127, j = i & 7;
    int k = step * 16 + hi * 8 + j;
    Wfa1[i] = f2bf(Wa1[(size_t)k * 128 + n]);
  } else if (idx < 234496) {
    int i = idx - 218112;
    int step = i >> 11, hi = (i >> 10) & 1;
    int n = (i >> 3) & 127, j = i & 7;
    int k = step * 16 + hi * 8 + j;
    Wfa2[i] = f2bf(Wa2[(size_t)k * 128 + n]);
  }
}

// ---------------- parallel 3-phase CSR scan ----------------
__global__ __launch_bounds__(1024) void scan1(const int* __restrict__ deg,
                                              int* __restrict__ partials, int N)
{
  __shared__ int red[16];
  int t = threadIdx.x;
  int n = blockIdx.x * 1024 + t;
  int v = (n < N) ? deg[n] : 0;
  for (int off = 32; off > 0; off >>= 1) v += __shfl_down(v, off);
  if ((t & 63) == 0) red[t >> 6] = v;
  __syncthreads();
  if (t == 0) {
    int s = 0;
    #pragma unroll
    for (int i = 0; i < 16; i++) s += red[i];
    partials[blockIdx.x] = s;
  }
}

__global__ __launch_bounds__(64) void scan2(int* __restrict__ partials,
                                            int* __restrict__ offsets, int B, int N)
{
  __shared__ int sp[64];
  int t = threadIdx.x;
  sp[t] = (t < B) ? partials[t] : 0;
  __syncthreads();
  if (t == 0) {
    int run = 0;
    for (int i = 0; i < B; i++) { int v = sp[i]; sp[i] = run; run += v; }
    offsets[N] = run;
  }
  __syncthreads();
  if (t < B) partials[t] = sp[t];
}

// zflag granularity = 32 (msg tile is 32 edges)
__global__ __launch_bounds__(1024) void scan3(const int* __restrict__ deg,
                                              const int* __restrict__ partials,
                                              int* __restrict__ offsets,
                                              int* __restrict__ cursor,
                                              int* __restrict__ zflag,
                                              const int* __restrict__ pos,
                                              int* __restrict__ inv, int N)
{
  __shared__ int s[1024];
  int t = threadIdx.x;
  int n = blockIdx.x * 1024 + t;
  int d = (n < N) ? deg[n] : 0;
  s[t] = d;
  __syncthreads();
  for (int off = 1; off < 1024; off <<= 1) {
    int v = 0;
    if (t >= off) v = s[t - off];
    __syncthreads();
    if (t >= off) s[t] += v;
    __syncthreads();
  }
  if (n < N) {
    int off = partials[blockIdx.x] + s[t] - d;   // exclusive prefix
    offsets[n] = off; cursor[n] = off;
    zflag[n] = (d == 0) || ((off >> 5) != ((off + d - 1) >> 5)) ? 1 : 0;
    inv[pos[n]] = n;
  }
}

__global__ __launch_bounds__(256) void scatter_csr(const int* __restrict__ to_idx,
                                                   int* __restrict__ cursor,
                                                   int* __restrict__ elist, int E)
{
  for (int e = blockIdx.x * 256 + threadIdx.x; e < E; e += gridDim.x * 256) {
    int pos = atomicAdd(&cursor[to_idx[e]], 1);
    elist[pos] = e;
  }
}

// ---------------- one-shot edge encoder: eenc = ef@We + be (CSR order, 64-dim bf16) ----------------
__global__ __launch_bounds__(256, 4) void enc_edges(
    const float* __restrict__ ef, const int* __restrict__ elist,
    const short* __restrict__ Wfe, const float* __restrict__ b_edge,
    short* __restrict__ eenc, int E)
{
  __shared__ short sE[64 * 24];
  __shared__ int eid_s[64];

  int t = threadIdx.x;
  int ln = t & 63, w = t >> 6;
  int l31 = ln & 31, hi = ln >> 5;
  int e0 = blockIdx.x * 64;

  if (t < 64) eid_s[t] = (e0 + t < E) ? elist[e0 + t] : 0;
  __syncthreads();

  {
    int r = t >> 2, q = t & 3;
    float4 v = *(const float4*)(ef + (size_t)eid_s[r] * 16 + q * 4);
    int2 s;
    s.x = (int)f2bf_pk(v.x, v.y);
    s.y = (int)f2bf_pk(v.z, v.w);
    *(int2*)(sE + r * 24 + q * 4) = s;
  }
  __syncthreads();

  {
    int rowb = (w & 1) * 32, cbq = (w >> 1) * 32;
    floatx16 acc;
    #pragma unroll
    for (int i = 0; i < 16; i++) acc[i] = 0.f;
    short8 a = *(const short8*)(sE + (rowb + l31) * 24 + hi * 8);
    short8 b = *(const short8*)(Wfe + (size_t)hi * 512 + (cbq + l31) * 8);
    acc = __builtin_amdgcn_mfma_f32_32x32x16_bf16(a, b, acc, 0, 0, 0);
    int col = cbq + l31;
    float bv = b_edge[col];
    #pragma unroll
    for (int reg = 0; reg < 16; reg++) {
      int row = rowb + (reg & 3) + 8 * (reg >> 2) + 4 * hi;
      eenc[(size_t)(e0 + row) * 64 + col] = f2bf(acc[reg] + bv);
    }
  }
}

// ---------------- node encoder + fused P1/P2 ----------------
__global__ __launch_bounds__(256, 3) void enc_nodes_p(
    const float* __restrict__ nf, const short* __restrict__ Wfn,
    const float* __restrict__ b_node, float* __restrict__ h,
    short* __restrict__ hb,
    const short* __restrict__ Wf1a, const short* __restrict__ Wf1b,
    short* __restrict__ P1f, short* __restrict__ P2f, int N)
{
  __shared__ short sN[32 * 40];
  __shared__ short sH[32 * 136];
  int t = threadIdx.x;
  int ln = t & 63, w = t >> 6;
  int l31 = ln & 31, hi = ln >> 5;
  int n0 = blockIdx.x * 32;

  {
    int r = t >> 3, q = t & 7;
    float4 v = {0.f, 0.f, 0.f, 0.f};
    if (n0 + r < N) v = *(const float4*)(nf + (size_t)(n0 + r) * 32 + q * 4);
    int2 s;
    s.x = (int)f2bf_pk(v.x, v.y);
    s.y = (int)f2bf_pk(v.z, v.w);
    *(int2*)(sN + r * 40 + q * 4) = s;
  }
  __syncthreads();

  int col = w * 32 + l31;
  {
    floatx16 acc;
    #pragma unroll
    for (int i = 0; i < 16; i++) acc[i] = 0.f;
    #pragma unroll
    for (int step = 0; step < 2; step++) {
      short8 a = *(const short8*)(sN + l31 * 40 + step * 16 + hi * 8);
      short8 b = *(const short8*)(Wfn + (size_t)(step * 2 + hi) * 1024 + col * 8);
      acc = __builtin_amdgcn_mfma_f32_32x32x16_bf16(a, b, acc, 0, 0, 0);
    }
    float bv = b_node[col];
    #pragma unroll
    for (int reg = 0; reg < 16; reg++) {
      int row = (reg & 3) + 8 * (reg >> 2) + 4 * hi;
      int n = n0 + row;
      float v = acc[reg] + bv;
      short bf = f2bf(v);
      if (n < N) {
        h[(size_t)n * 128 + col] = v;
        hb[(size_t)n * 128 + col] = bf;
      }
      sH[row * 136 + col] = bf;
    }
  }
  __syncthreads();

  int cb = w * 64;
  const int arow = l31 * 136;
  const int bc0 = (cb + l31) * 8, bc1 = (cb + 32 + l31) * 8;
  floatx16 acc[2][2];
  #pragma unroll
  for (int o = 0; o < 2; o++)
    #pragma unroll
    for (int ct = 0; ct < 2; ct++)
      #pragma unroll
      for (int i = 0; i < 16; i++) acc[o][ct][i] = 0.f;

  #pragma unroll
  for (int step = 0; step < 8; step++) {
    short8 a = *(const short8*)(sH + arow + step * 16 + hi * 8);
    short8 ba0 = *(const short8*)(Wf1a + (size_t)(step * 2 + hi) * 2048 + bc0);
    short8 ba1 = *(const short8*)(Wf1a + (size_t)(step * 2 + hi) * 2048 + bc1);
    short8 bb0 = *(const short8*)(Wf1b + (size_t)(step * 2 + hi) * 2048 + bc0);
    short8 bb1 = *(const short8*)(Wf1b + (size_t)(step * 2 + hi) * 2048 + bc1);
    acc[0][0] = __builtin_amdgcn_mfma_f32_32x32x16_bf16(a, ba0, acc[0][0], 0, 0, 0);
    acc[0][1] = __builtin_amdgcn_mfma_f32_32x32x16_bf16(a, ba1, acc[0][1], 0, 0, 0);
    acc[1][0] = __builtin_amdgcn_mfma_f32_32x32x16_bf16(a, bb0, acc[1][0], 0, 0, 0);
    acc[1][1] = __builtin_amdgcn_mfma_f32_32x32x16_bf16(a, bb1, acc[1][1], 0, 0, 0);
  }

  #pragma unroll
  for (int ct = 0; ct < 2; ct++) {
    int pcol = cb + ct * 32 + l31;
    #pragma unroll
    for (int reg = 0; reg < 16; reg++) {
      int row = (reg & 3) + 8 * (reg >> 2) + 4 * hi;
      int n = n0 + row;
      if (n < N) {
        P1f[(size_t)n * 256 + pcol] = f2bf(acc[0][ct][reg]);
        P2f[(size_t)n * 256 + pcol] = f2bf(acc[1][ct][reg]);
      }
    }
  }
}

// ---------------- fused message step (32-edge tile): eenc GEMM + relu(P1+P2+Pe) + CSR segment-sum ----------------
// eenc precomputed in CSR order (step-invariant): staging is a coalesced bf16 copy,
// GEMM1 and one barrier removed vs r12. GEMM2/RMW/walk bit-identical.
__global__ __launch_bounds__(256, 6) void msg_agg(
    const short* __restrict__ eenc,
    const short* __restrict__ Wf1e, const float* __restrict__ b1,
    const short* __restrict__ P1f, const short* __restrict__ P2f,
    const int* __restrict__ elist,
    const int* __restrict__ from_idx, const int* __restrict__ to_idx,
    const int* __restrict__ offsets,
    float* __restrict__ agg, int E)
{
  __shared__ short sEn[32 * 68];
  __shared__ short sA[32 * 264];
  __shared__ int from_s[32], to_s[32];
  __shared__ int rend_s[32], inter_s[32];

  int t = threadIdx.x;
  int ln = t & 63, w = t >> 6;
  int l31 = ln & 31, hi = ln >> 5;
  int e0 = blockIdx.x * 32;

  if (t < 32) {
    int idx = e0 + t;
    int eid = (idx < E) ? elist[idx] : 0;
    from_s[t] = from_idx[eid];
    to_s[t] = (idx < E) ? to_idx[eid] : -1;
  }

  // stage eenc rows (contiguous CSR order, pure bf16 copy): 32 rows x 8 short8
  for (int i = t; i < 256; i += 256) {
    int r = i >> 3, c = i & 7;
    short8 v = *(const short8*)(eenc + (size_t)(e0 + r) * 64 + c * 8);
    *(short8*)(sEn + r * 68 + c * 8) = v;
  }
  __syncthreads();

  if (t < 32) {
    int nd = to_s[t];
    bool head = (t == 0) || (nd != to_s[t - 1]);
    if (head && nd >= 0) {
      int re = t + 1;
      while (re < 32 && to_s[re] == nd) re++;
      rend_s[t] = re;
      inter_s[t] = (offsets[nd] == e0 + t) && (offsets[nd + 1] == e0 + re) ? 1 : 0;
    }
  }
  __syncthreads();

  // GEMM: Pe[32x256] = sEn @ Wf1e + b1 -> sA (bf16); wave w owns 64-col quadrant
  {
    const int cb = w * 64;
    const int bc0 = (cb + l31) * 8, bc1 = (cb + 32 + l31) * 8;
    floatx16 acc[2];
    #pragma unroll
    for (int ct = 0; ct < 2; ct++)
      #pragma unroll
      for (int i = 0; i < 16; i++) acc[ct][i] = 0.f;

    #pragma unroll
    for (int step = 0; step < 4; step++) {
      short8 a = *(const short8*)(sEn + l31 * 68 + step * 16 + hi * 8);
      short8 b0 = *(const short8*)(Wf1e + (size_t)(step * 2 + hi) * 2048 + bc0);
      short8 b1v = *(const short8*)(Wf1e + (size_t)(step * 2 + hi) * 2048 + bc1);
      acc[0] = __builtin_amdgcn_mfma_f32_32x32x16_bf16(a, b0,  acc[0], 0, 0, 0);
      acc[1] = __builtin_amdgcn_mfma_f32_32x32x16_bf16(a, b1v, acc[1], 0, 0, 0);
    }

    #pragma unroll
    for (int ct = 0; ct < 2; ct++) {
      int col = cb + ct * 32 + l31;
      float bv = b1[col];
      #pragma unroll
      for (int reg = 0; reg < 16; reg++) {
        int row = (reg & 3) + 8 * (reg >> 2) + 4 * hi;
        sA[row * 264 + col] = f2bf(acc[ct][reg] + bv);
      }
    }
  }
  __syncthreads();

  // RMW: sA = relu(P1[from] + P2[to] + sA)
  for (int i = t; i < 1024; i += 256) {
    int r = i >> 5, c8 = (i & 31) * 8;
    int nd = to_s[r]; if (nd < 0) nd = 0;
    short8 a = *(const short8*)(P1f + (size_t)from_s[r] * 256 + c8);
    short8 b = *(const short8*)(P2f + (size_t)nd * 256 + c8);
    short8 c = *(short8*)(sA + r * 264 + c8);
    float v[8];
    #pragma unroll
    for (int j = 0; j < 8; j++)
      v[j] = fmaxf(bf2f(a[j]) + bf2f(b[j]) + bf2f(c[j]), 0.f);
    int4 pk;
    pk.x = (int)f2bf_pk(v[0], v[1]);
    pk.y = (int)f2bf_pk(v[2], v[3]);
    pk.z = (int)f2bf_pk(v[4], v[5]);
    pk.w = (int)f2bf_pk(v[6], v[7]);
    *(int4*)(sA + r * 264 + c8) = pk;
  }
  __syncthreads();

  // CSR segment walk -> agg
  {
    int c = t;
    for (int r = 0; r < 32; ) {
      int nd = to_s[r];
      if (nd < 0) break;
      int re = rend_s[r];
      float a = 0.f;
      for (int i = r; i < re; i++)
        a += bf2f(sA[i * 264 + c]);
      float* dst = agg + (size_t)nd * 256 + c;
      if (inter_s[r]) *dst = a;
      else unsafeAtomicAdd(dst, a);
      r = re;
    }
  }
}

// ---------------- node update: GEMM2 (S@W2 + deg*b2) + update GEMM + fused P1/P2 ----------------
__global__ __launch_bounds__(256, 4) void update_mfma_p(
    float* __restrict__ h, short* __restrict__ hbf, float* __restrict__ agg,
    const short* __restrict__ Wf2, const float* __restrict__ b2,
    const int* __restrict__ deg,
    const short* __restrict__ Wfu, const float* __restrict__ bu,
    const short* __restrict__ Wf1a, const short* __restrict__ Wf1b,
    short* __restrict__ P1f, short* __restrict__ P2f,
    const int* __restrict__ zflag, int want_p, int N)
{
  __shared__ short sA2[32 * 136];
  __shared__ short sS[32 * 264];
  __shared__ int zf_s[32];
  __shared__ int deg_s[32];

  int t = threadIdx.x;
  int ln = t & 63, w = t >> 6;
  int l31 = ln & 31, hi = ln >> 5;
  int n0 = blockIdx.x * 32;

  if (t < 32) {
    zf_s[t] = (n0 + t < N) ? zflag[n0 + t] : 0;
    deg_s[t] = (n0 + t < N) ? deg[n0 + t] : 0;
  }

  for (int i = t; i < 512; i += 256) {
    int r = i >> 4, c = i & 15;
    short8 v = {0, 0, 0, 0, 0, 0, 0, 0};
    if (n0 + r < N) v = *(const short8*)(hbf + (size_t)(n0 + r) * 128 + c * 8);
    *(short8*)(sA2 + r * 136 + c * 8) = v;
  }
  for (int i = t; i < 2048; i += 256) {
    int r = i >> 6, c4 = i & 63;
    int2 pk = {0, 0};
    if (n0 + r < N) {
      float4 v = *(const float4*)(agg + (size_t)(n0 + r) * 256 + c4 * 4);
      pk.x = (int)f2bf_pk(v.x, v.y);
      pk.y = (int)f2bf_pk(v.z, v.w);
    }
    *(int2*)(sS + r * 264 + c4 * 4) = pk;
  }
  __syncthreads();

  {
    float4 z = {0.f, 0.f, 0.f, 0.f};
    for (int i = t; i < 2048; i += 256) {
      int r = i >> 6, c4 = i & 63;
      if (n0 + r < N && zf_s[r])
        *(float4*)(agg + (size_t)(n0 + r) * 256 + c4 * 4) = z;
    }
  }

  // GEMM2: M[32x256] = sS @ Wf2 (accumulate in registers)
  floatx16 macc[2];
  int cb2 = w * 64;
  {
    const int bc0 = (cb2 + l31) * 8, bc1 = (cb2 + 32 + l31) * 8;
    #pragma unroll
    for (int ct = 0; ct < 2; ct++)
      #pragma unroll
      for (int i = 0; i < 16; i++) macc[ct][i] = 0.f;

    #pragma unroll
    for (int step = 0; step < 16; step++) {
      short8 a = *(const short8*)(sS + l31 * 264 + step * 16 + hi * 8);
      short8 b0 = *(const short8*)(Wf2 + (size_t)(step * 2 + hi) * 2048 + bc0);
      short8 b1v = *(const short8*)(Wf2 + (size_t)(step * 2 + hi) * 2048 + bc1);
      macc[0] = __builtin_amdgcn_mfma_f32_32x32x16_bf16(a, b0,  macc[0], 0, 0, 0);
      macc[1] = __builtin_amdgcn_mfma_f32_32x32x16_bf16(a, b1v, macc[1], 0, 0, 0);
    }
  }
  __syncthreads();   // all waves done READING sS -> safe to overwrite

  // write M + deg*b2 (bf16) in place of sS
  {
    #pragma unroll
    for (int ct = 0; ct < 2; ct++) {
      int col = cb2 + ct * 32 + l31;
      float bv2 = b2[col];
      #pragma unroll
      for (int reg = 0; reg < 16; reg++) {
        int row = (reg & 3) + 8 * (reg >> 2) + 4 * hi;
        sS[row * 264 + col] = f2bf(macc[ct][reg] + (float)deg_s[row] * bv2);
      }
    }
  }
  __syncthreads();

  // update GEMM: A = [hbf | M] -> steps 0..7 from sA2, steps 8..23 from sS
  const int bcol = (w * 32 + l31) * 8;

  floatx16 acc;
  #pragma unroll
  for (int i = 0; i < 16; i++) acc[i] = 0.f;

  {
    auto aptr = [&](int step) -> const short* {
      int kb = step * 16 + hi * 8;
      return (step < 8) ? (sA2 + l31 * 136 + kb) : (sS + l31 * 264 + (kb - 128));
    };
    short8 bbuf[3];
    #pragma unroll
    for (int s = 0; s < 3; s++)
      bbuf[s] = *(const short8*)(Wfu + (size_t)(s * 2 + hi) * 1024 + bcol);
    short8 abuf[2];
    abuf[0] = *(const short8*)aptr(0);
    #pragma unroll
    for (int step = 0; step < 24; step++) {
      if (step + 1 < 24)
        abuf[(step + 1) & 1] = *(const short8*)aptr(step + 1);
      acc = __builtin_amdgcn_mfma_f32_32x32x16_bf16(abuf[step & 1], bbuf[step % 3], acc, 0, 0, 0);
      if (step + 3 < 24)
        bbuf[step % 3] = *(const short8*)(Wfu + (size_t)((step + 3) * 2 + hi) * 1024 + bcol);
    }
  }

  __syncthreads();

  int col = w * 32 + l31;
  float bv = bu[col];
  #pragma unroll
  for (int reg = 0; reg < 16; reg++) {
    int row = (reg & 3) + 8 * (reg >> 2) + 4 * hi;
    int n = n0 + row;
    float nv = 0.f;
    if (n < N) nv = h[(size_t)n * 128 + col] + acc[reg] + bv;
    short bf = f2bf(nv);
    if (n < N) {
      h[(size_t)n * 128 + col] = nv;
      hbf[(size_t)n * 128 + col] = bf;
    }
    sA2[row * 136 + col] = bf;
  }

  if (!want_p) return;
  __syncthreads();

  int cb = w * 64;
  const int bc0 = (cb + l31) * 8, bc1 = (cb + 32 + l31) * 8;
  const int arow = l31 * 136;
  floatx16 pacc[2][2];
  #pragma unroll
  for (int o = 0; o < 2; o++)
    #pragma unroll
    for (int ct = 0; ct < 2; ct++)
      #pragma unroll
      for (int i = 0; i < 16; i++) pacc[o][ct][i] = 0.f;

  #pragma unroll
  for (int step = 0; step < 8; step++) {
    short8 a = *(const short8*)(sA2 + arow + step * 16 + hi * 8);
    short8 ba0 = *(const short8*)(Wf1a + (size_t)(step * 2 + hi) * 2048 + bc0);
    short8 ba1 = *(const short8*)(Wf1a + (size_t)(step * 2 + hi) * 2048 + bc1);
    short8 bb0 = *(const short8*)(Wf1b + (size_t)(step * 2 + hi) * 2048 + bc0);
    short8 bb1 = *(const short8*)(Wf1b + (size_t)(step * 2 + hi) * 2048 + bc1);
    pacc[0][0] = __builtin_amdgcn_mfma_f32_32x32x16_bf16(a, ba0, pacc[0][0], 0, 0, 0);
    pacc[0][1] = __builtin_amdgcn_mfma_f32_32x32x16_bf16(a, ba1, pacc[0][1], 0, 0, 0);
    pacc[1][0] = __builtin_amdgcn_mfma_f32_32x32x16_bf16(a, bb0, pacc[1][0], 0, 0, 0);
    pacc[1][1] = __builtin_amdgcn_mfma_f32_32x32x16_bf16(a, bb1, pacc[1][1], 0, 0, 0);
  }

  #pragma unroll
  for (int ct = 0; ct < 2; ct++) {
    int pcol = cb + ct * 32 + l31;
    #pragma unroll
    for (int reg = 0; reg < 16; reg++) {
      int row = (reg & 3) + 8 * (reg >> 2) + 4 * hi;
      int n = n0 + row;
      if (n < N) {
        P1f[(size_t)n * 256 + pcol] = f2bf(pacc[0][ct][reg]);
        P2f[(size_t)n * 256 + pcol] = f2bf(pacc[1][ct][reg]);
      }
    }
  }
}

// ---------------- fused stack + attention features ----------------
__global__ __launch_bounds__(256, 3) void stack_attfeat(
    const float* __restrict__ h, const int* __restrict__ inv,
    const short* __restrict__ Wfa1, const float* __restrict__ ba1,
    const short* __restrict__ Wfa2, const float* __restrict__ ba2,
    const int* __restrict__ qsizes, const int* __restrict__ csizes,
    float* __restrict__ flat, short* __restrict__ flatT, short* __restrict__ tfb)
{
  __shared__ short sA[64 * 136];
  __shared__ int nd_s[64];

  int t = threadIdx.x;
  int ln = t & 63, w = t >> 6;
  int l31 = ln & 31, hi = ln >> 5;
  int r0 = blockIdx.x * 64;

  if (t < 64) nd_s[t] = inv[r0 + t];
  __syncthreads();

  for (int i = t; i < 1024; i += 256) {
    int r = i >> 4, c = (i & 15) * 8;
    int nd = nd_s[r];
    float4 v0 = {0.f, 0.f, 0.f, 0.f}, v1 = {0.f, 0.f, 0.f, 0.f};
    if (nd >= 0) {
      v0 = *(const float4*)(h + (size_t)nd * 128 + c);
      v1 = *(const float4*)(h + (size_t)nd * 128 + c + 4);
    }
    *(float4*)(flat + (size_t)(r0 + r) * 128 + c) = v0;
    *(float4*)(flat + (size_t)(r0 + r) * 128 + c + 4) = v1;
    int4 s;
    s.x = (int)f2bf_pk(v0.x, v0.y);
    s.y = (int)f2bf_pk(v0.z, v0.w);
    s.z = (int)f2bf_pk(v1.x, v1.y);
    s.w = (int)f2bf_pk(v1.z, v1.w);
    *(int4*)(sA + r * 136 + c) = s;
  }
  __syncthreads();

  for (int i = t; i < 8192; i += 256) {
    int d = i >> 6, r = i & 63;
    flatT[(size_t)blockIdx.x * 8192 + d * 64 + r] = sA[r * 136 + d];
  }

  const int arow0 = l31 * 136, arow1 = (32 + l31) * 136;
  const int bcol = (w * 32 + l31) * 8;
  int col = w * 32 + l31;

  floatx16 acc[2];
  #pragma unroll
  for (int rg = 0; rg < 2; rg++)
    #pragma unroll
    for (int i = 0; i < 16; i++) acc[rg][i] = 0.f;

  #pragma unroll
  for (int step = 0; step < 8; step++) {
    short8 a0 = *(const short8*)(sA + arow0 + step * 16 + hi * 8);
    short8 a1 = *(const short8*)(sA + arow1 + step * 16 + hi * 8);
    short8 bfr = *(const short8*)(Wfa1 + (size_t)(step * 2 + hi) * 1024 + bcol);
    acc[0] = __builtin_amdgcn_mfma_f32_32x32x16_bf16(a0, bfr, acc[0], 0, 0, 0);
    acc[1] = __builtin_amdgcn_mfma_f32_32x32x16_bf16(a1, bfr, acc[1], 0, 0, 0);
  }

  __syncthreads();
  {
    float bv = ba1[col];
    #pragma unroll
    for (int rg = 0; rg < 2; rg++)
      #pragma unroll
      for (int reg = 0; reg < 16; reg++) {
        int row = rg * 32 + (reg & 3) + 8 * (reg >> 2) + 4 * hi;
        sA[row * 136 + col] = f2bf(fmaxf(acc[rg][reg] + bv, 0.f));
      }
  }
  __syncthreads();

  floatx16 acc2[2];
  #pragma unroll
  for (int rg = 0; rg < 2; rg++)
    #pragma unroll
    for (int i = 0; i < 16; i++) acc2[rg][i] = 0.f;

  #pragma unroll
  for (int step = 0; step < 8; step++) {
    short8 a0 = *(const short8*)(sA + arow0 + step * 16 + hi * 8);
    short8 a1 = *(const short8*)(sA + arow1 + step * 16 + hi * 8);
    short8 bfr = *(const short8*)(Wfa2 + (size_t)(step * 2 + hi) * 1024 + bcol);
    acc2[0] = __builtin_amdgcn_mfma_f32_32x32x16_bf16(a0, bfr, acc2[0], 0, 0, 0);
    acc2[1] = __builtin_amdgcn_mfma_f32_32x32x16_bf16(a1, bfr, acc2[1], 0, 0, 0);
  }

  {
    float bv = ba2[col];
    #pragma unroll
    for (int rg = 0; rg < 2; rg++)
      #pragma unroll
      for (int reg = 0; reg < 16; reg++) {
        int row = r0 + rg * 32 + (reg & 3) + 8 * (reg >> 2) + 4 * hi;
        int part = row >> 14, b = (row >> 6) & 255, pp = row & 63;
        int sz = part ? csizes[b] : qsizes[b];
        float m = (pp < sz) ? 1.f : 0.f;
        tfb[(size_t)row * 128 + col] = f2bf((acc2[rg][reg] + bv) * m);
      }
  }
}

// ---------------- per-pair score: MFMA logits + parallel softmax + MFMA PV ----------------
__global__ __launch_bounds__(256, 3) void score_kernel(
    const short* __restrict__ tfb, const float* __restrict__ flat,
    const short* __restrict__ flatT,
    const int* __restrict__ qsizes, const int* __restrict__ csizes,
    float* __restrict__ out)
{
  __shared__ float SL[64 * 65];
  __shared__ float SP2[64 * 65];
  __shared__ float rstat[128];
  __shared__ float cstat[128];
  __shared__ float red[8];

  int b = blockIdx.x, t = threadIdx.x;
  int ln = t & 63, w = t >> 6;
  int l31 = ln & 31, hi = ln >> 5;
  const short* tqb = tfb + (size_t)b * 8192;
  const short* tcb = tfb + (size_t)(256 + b) * 8192;
  const float* sq = flat + (size_t)b * 8192;
  const float* sc = flat + (size_t)(256 + b) * 8192;
  const short* sqT = flatT + (size_t)b * 8192;
  const short* scT = flatT + (size_t)(256 + b) * 8192;
  int qs = qsizes[b], cs = csizes[b];

  {
    int rowb = (w & 1) * 32, cbq = (w >> 1) * 32;
    floatx16 acc;
    #pragma unroll
    for (int i = 0; i < 16; i++) acc[i] = 0.f;
    #pragma unroll
    for (int step = 0; step < 8; step++) {
      short8 a  = *(const short8*)(tqb + (size_t)(rowb + l31) * 128 + step * 16 + hi * 8);
      short8 bf = *(const short8*)(tcb + (size_t)(cbq + l31) * 128 + step * 16 + hi * 8);
      acc = __builtin_amdgcn_mfma_f32_32x32x16_bf16(a, bf, acc, 0, 0, 0);
    }
    int ccol = cbq + l31;
    #pragma unroll
    for (int reg = 0; reg < 16; reg++) {
      int qrow = rowb + (reg & 3) + 8 * (reg >> 2) + 4 * hi;
      SL[qrow * 65 + ccol] = (qrow < qs && ccol < cs) ? acc[reg] * 10.0f : -1e9f;
    }
  }
  __syncthreads();

  {
    int q = t >> 2, g = t & 3;
    const float* row = SL + q * 65 + g * 16;
    float m = -1e30f;
    #pragma unroll
    for (int i = 0; i < 16; i++) m = fmaxf(m, row[i]);
    m = fmaxf(m, __shfl_xor(m, 1));
    m = fmaxf(m, __shfl_xor(m, 2));
    float s = 0.f;
    #pragma unroll
    for (int i = 0; i < 16; i++) s += __expf(row[i] - m);
    s += __shfl_xor(s, 1);
    s += __shfl_xor(s, 2);
    if (g == 0) { rstat[q] = m; rstat[64 + q] = 1.0f / s; }
  }
  {
    int c = t >> 2, g = t & 3;
    const float* colp = SL + (g * 16) * 65 + c;
    float m = -1e30f;
    #pragma unroll
    for (int i = 0; i < 16; i++) m = fmaxf(m, colp[i * 65]);
    m = fmaxf(m, __shfl_xor(m, 1));
    m = fmaxf(m, __shfl_xor(m, 2));
    float s = 0.f;
    #pragma unroll
    for (int i = 0; i < 16; i++) s += __expf(colp[i * 65] - m);
    s += __shfl_xor(s, 1);
    s += __shfl_xor(s, 2);
    if (g == 0) { cstat[c] = m; cstat[64 + c] = 1.0f / s; }
  }
  __syncthreads();

  {
    int q = t >> 2, g = t & 3;
    float rm = rstat[q], ri = rstat[64 + q];
    bool qv = q < qs;
    #pragma unroll
    for (int i = 0; i < 16; i++) {
      int c = g * 16 + i;
      float v = SL[q * 65 + c];
      SL[q * 65 + c]  = qv ? __expf(v - rm) * ri : 0.f;
      SP2[q * 65 + c] = (c < cs) ? __expf(v - cstat[c]) * cstat[64 + c] : 0.f;
    }
  }
  __syncthreads();

  int dcol = w * 32 + l31;
  floatx16 accq[2], accc[2];
  #pragma unroll
  for (int rt = 0; rt < 2; rt++) {
    #pragma unroll
    for (int i = 0; i < 16; i++) { accq[rt][i] = 0.f; accc[rt][i] = 0.f; }
  }

  #pragma unroll
  for (int rt = 0; rt < 2; rt++) {
    #pragma unroll
    for (int step = 0; step < 4; step++) {
      int kb = step * 16 + hi * 8;
      int row = rt * 32 + l31;
      short8 a;
      #pragma unroll
      for (int j = 0; j < 8; j++) a[j] = f2bf(SL[row * 65 + kb + j]);
      short8 bf = *(const short8*)(scT + (size_t)dcol * 64 + kb);
      accq[rt] = __builtin_amdgcn_mfma_f32_32x32x16_bf16(a, bf, accq[rt], 0, 0, 0);
    }
  }
  #pragma unroll
  for (int rt = 0; rt < 2; rt++) {
    #pragma unroll
    for (int step = 0; step < 4; step++) {
      int kb = step * 16 + hi * 8;
      int crow = rt * 32 + l31;
      short8 a;
      #pragma unroll
      for (int j = 0; j < 8; j++) a[j] = f2bf(SP2[(kb + j) * 65 + crow]);
      short8 bf = *(const short8*)(sqT + (size_t)dcol * 64 + kb);
      accc[rt] = __builtin_amdgcn_mfma_f32_32x32x16_bf16(a, bf, accc[rt], 0, 0, 0);
    }
  }

  float qpart = 0.f, cpart = 0.f;
  #pragma unroll
  for (int rt = 0; rt < 2; rt++) {
    #pragma unroll
    for (int reg = 0; reg < 16; reg++) {
      int row = rt * 32 + (reg & 3) + 8 * (reg >> 2) + 4 * hi;
      qpart += fmaxf(sq[(size_t)row * 128 + dcol] - accq[rt][reg], 0.f);
      cpart += fmaxf(sc[(size_t)row * 128 + dcol] - accc[rt][reg], 0.f);
    }
  }

  for (int off = 32; off > 0; off >>= 1) {
    qpart += __shfl_down(qpart, off);
    cpart += __shfl_down(cpart, off);
  }
  if ((t & 63) == 0) { red[w] = qpart; red[w + 4] = cpart; }
  __syncthreads();
  if (t == 0) {
    float qsum = red[0] + red[1] + red[2] + red[3];
    float csum = red[4] + red[5] + red[6] + red[7];
    out[b] = fminf(-qsum, -csum);
  }
}

// ---------------- launch ----------------
extern "C" void kernel_launch(void* const* d_in, const int* in_sizes, int n_in,
                              void* d_out, int out_size, void* d_ws, size_t ws_size,
                              hipStream_t stream)
{
  const float* nf  = (const float*)d_in[0];
  const float* ef  = (const float*)d_in[1];
  const int* from_idx = (const int*)d_in[2];
  const int* to_idx   = (const int*)d_in[3];
  const int* pos      = (const int*)d_in[4];
  const int* qsz      = (const int*)d_in[5];
  const int* csz      = (const int*)d_in[6];
  const float* W_node = (const float*)d_in[7];
  const float* b_node = (const float*)d_in[8];
  const float* W_edge = (const float*)d_in[9];
  const float* b_edge = (const float*)d_in[10];
  const float* W1 = (const float*)d_in[11];
  const float* b1 = (const float*)d_in[12];
  const float* W2 = (const float*)d_in[13];
  const float* b2 = (const float*)d_in[14];
  const float* Wu = (const float*)d_in[15];
  const float* bu = (const float*)d_in[16];
  const float* Wa1 = (const float*)d_in[17];
  const float* ba1 = (const float*)d_in[18];
  const float* Wa2 = (const float*)d_in[19];
  const float* ba2 = (const float*)d_in[20];
  float* out = (float*)d_out;

  int N = in_sizes[0] / NODE_F;
  int E = in_sizes[1] / EDGE_F;
  int Epad32 = (E + 31) & ~31;
  int Epad64 = (E + 63) & ~63;
  int PAD = 2 * B_PAIRS * MAXN;   // 32768
  int NB = (N + 1023) / 1024;     // scan blocks (<=64 for N<=65536)

  float* h    = (float*)d_ws;                              // N*128 f32
  float* agg  = h + (size_t)N * D;                         // N*256 f32 (sum of relu)
  short* hb   = (short*)(agg + (size_t)N * 256);           // N*128 bf16
  short* P1f  = hb + (size_t)N * D;                        // N*256 bf16
  short* P2f  = P1f + (size_t)N * 256;                     // N*256 bf16
  short* Wfn  = P2f + (size_t)N * 256;                     // 4096
  short* Wfe  = Wfn + 4096;                                // 1024
  short* Wf1a = Wfe + 1024;                                // 32768
  short* Wf1b = Wf1a + 32768;                              // 32768
  short* Wf1e = Wf1b + 32768;                              // 16384
  short* Wf2  = Wf1e + 16384;                              // 65536
  short* Wfu  = Wf2 + 65536;                               // 49152
  short* Wfa1 = Wfu + 49152;                               // 16384
  short* Wfa2 = Wfa1 + 16384;                              // 16384
  int*   deg     = (int*)(Wfa2 + 16384);                   // N
  int*   offsets = deg + N;                                // N+1
  int*   cursor  = offsets + N + 1;                        // N
  int*   elist   = cursor + N;                             // E
  int*   inv     = elist + E;                              // PAD
  int*   zflag   = inv + PAD;                              // N
  int*   partials = zflag + N;                             // NB (<=64)
  uintptr_t pb = ((uintptr_t)(partials + 64) + 15) & ~(uintptr_t)15;
  float* flat  = (float*)pb;                               // PAD*128 f32
  short* flatT = (short*)(flat + (size_t)PAD * D);
  short* tfb16 = flatT + (size_t)PAD * D;
  short* eenc  = tfb16 + (size_t)PAD * D;                  // Epad64*64 bf16 (CSR order)

  hipMemsetAsync(deg, 0, (size_t)N * sizeof(int), stream);
  init_kernel<<<916 + 256, 256, 0, stream>>>(
      W_node, W_edge, W1, W2, Wu, Wa1, Wa2,
      Wfn, Wfe, Wf1a, Wf1b, Wf1e, Wf2, Wfu, Wfa1, Wfa2,
      to_idx, deg, inv, E);
  scan1<<<NB, 1024, 0, stream>>>(deg, partials, N);
  scan2<<<1, 64, 0, stream>>>(partials, offsets, NB, N);
  scan3<<<NB, 1024, 0, stream>>>(deg, partials, offsets, cursor, zflag, pos, inv, N);
  scatter_csr<<<256, 256, 0, stream>>>(to_idx, cursor, elist, E);

  enc_edges<<<Epad64 / 64, 256, 0, stream>>>(ef, elist, Wfe, b_edge, eenc, E);
  enc_nodes_p<<<(N + 31) / 32, 256, 0, stream>>>(nf, Wfn, b_node, h, hb,
                                                 Wf1a, Wf1b, P1f, P2f, N);

  hipMemsetAsync(agg, 0, (size_t)N * 256 * sizeof(float), stream);

  for (int s = 0; s < PROP_STEPS; s++) {
    msg_agg<<<Epad32 / 32, 256, 0, stream>>>(eenc, Wf1e, b1, P1f, P2f, elist,
                                             from_idx, to_idx, offsets, agg, E);
    update_mfma_p<<<(N + 31) / 32, 256, 0, stream>>>(h, hb, agg, Wf2, b2, deg,
                                                     Wfu, bu, Wf1a, Wf1b, P1f, P2f, zflag,
                                                     (s + 1 < PROP_STEPS) ? 1 : 0, N);
  }

  stack_attfeat<<<PAD / 64, 256, 0, stream>>>(h, inv, Wfa1, ba1, Wfa2, ba2,
                                              qsz, csz, flat, flatT, tfb16);
  score_kernel<<<B_PAIRS, 256, 0, stream>>>(tfb16, flat, flatT, qsz, csz, out);
}